// Round 1
// baseline (3026.511 us; speedup 1.0000x reference)
//
#include <hip/hip_runtime.h>
#include <cstdint>

#define NN 100000
#define EE 1600000
#define HH 128

// ---------- monotone float<->uint encoding for atomicMax on floats ----------
__device__ __forceinline__ unsigned encf(float f) {
    int b = __float_as_int(f);
    return (b >= 0) ? ((unsigned)b | 0x80000000u) : ~(unsigned)b;
}
__device__ __forceinline__ float decf(unsigned u) {
    return (u & 0x80000000u) ? __int_as_float((int)(u & 0x7fffffffu))
                             : __int_as_float((int)(~u));
}
#define ENC_NEG_INF 0x007FFFFFu  // encf(-inf)

// ---------- init: deg=1 (self-loop weight), zero/neg-inf the small accumulators ----------
__global__ void k_init(float* __restrict__ deg, float* __restrict__ meansum,
                       unsigned* __restrict__ maxenc, unsigned* __restrict__ lmaxenc,
                       float* __restrict__ esum) {
    int i = blockIdx.x * blockDim.x + threadIdx.x;
    if (i < NN) deg[i] = 1.0f;
    if (i < HH) { meansum[i] = 0.f; maxenc[i] = ENC_NEG_INF; }
    if (i == 0) { lmaxenc[0] = ENC_NEG_INF; esum[0] = 0.f; }
}

// ---------- deg[i] += sum of edge weights with row==i ----------
__global__ void k_deg(const int* __restrict__ rows, const float* __restrict__ ea,
                      float* __restrict__ deg) {
    int e = blockIdx.x * blockDim.x + threadIdx.x;
    if (e < EE) atomicAdd(&deg[rows[e]], ea[e]);
}

__global__ void k_dis(const float* __restrict__ deg, float* __restrict__ dis) {
    int i = blockIdx.x * blockDim.x + threadIdx.x;
    if (i < NN) dis[i] = rsqrtf(deg[i]);  // deg >= 1 always (self-loop w=1, ea>=0)
}

// ---------- C[n,128] = (RELU?relu(A):A) @ W[128,128], fp32 VALU ----------
template <bool RELU>
__global__ __launch_bounds__(256) void k_gemm(const float* __restrict__ A,
                                              const float* __restrict__ W,
                                              float* __restrict__ C, int n) {
    __shared__ float As[64][HH];  // 32 KB
    const int t = threadIdx.x;
    const int rb = blockIdx.x * 64;
#pragma unroll
    for (int i = 0; i < 8; ++i) {
        int lin = i * 1024 + t * 4;
        int r = lin >> 7, k = lin & 127;
        float4 v = make_float4(0.f, 0.f, 0.f, 0.f);
        if (rb + r < n) {
            v = *(const float4*)(A + (size_t)(rb + r) * HH + k);
            if (RELU) {
                v.x = fmaxf(v.x, 0.f); v.y = fmaxf(v.y, 0.f);
                v.z = fmaxf(v.z, 0.f); v.w = fmaxf(v.w, 0.f);
            }
        }
        *(float4*)(&As[r][k]) = v;
    }
    __syncthreads();
    const int f0 = (t & 31) * 4;   // 4 output features
    const int r0 = (t >> 5) * 8;   // 8 rows
    float acc[8][4];
#pragma unroll
    for (int i = 0; i < 8; ++i)
#pragma unroll
        for (int c = 0; c < 4; ++c) acc[i][c] = 0.f;
    for (int k = 0; k < HH; k += 4) {
        float4 w0 = *(const float4*)(W + (size_t)(k + 0) * HH + f0);
        float4 w1 = *(const float4*)(W + (size_t)(k + 1) * HH + f0);
        float4 w2 = *(const float4*)(W + (size_t)(k + 2) * HH + f0);
        float4 w3 = *(const float4*)(W + (size_t)(k + 3) * HH + f0);
#pragma unroll
        for (int i = 0; i < 8; ++i) {
            float4 a = *(const float4*)(&As[r0 + i][k]);  // uniform per half-wave -> LDS broadcast
            acc[i][0] += a.x * w0.x + a.y * w1.x + a.z * w2.x + a.w * w3.x;
            acc[i][1] += a.x * w0.y + a.y * w1.y + a.z * w2.y + a.w * w3.y;
            acc[i][2] += a.x * w0.z + a.y * w1.z + a.z * w2.z + a.w * w3.z;
            acc[i][3] += a.x * w0.w + a.y * w1.w + a.z * w2.w + a.w * w3.w;
        }
    }
#pragma unroll
    for (int i = 0; i < 8; ++i) {
        int r = rb + r0 + i;
        if (r < n)
            *(float4*)(C + (size_t)r * HH + f0) =
                make_float4(acc[i][0], acc[i][1], acc[i][2], acc[i][3]);
    }
}

// ---------- agg[i][f] = bias[f] + hW[i][f]*dis[i]^2  (self-loop term + bias) ----------
__global__ void k_selfinit(const float* __restrict__ hW, const float* __restrict__ dis,
                           const float* __restrict__ bias, float* __restrict__ agg) {
    int idx = blockIdx.x * blockDim.x + threadIdx.x;  // float4 index, N*32 total
    if (idx >= NN * 32) return;
    int i = idx >> 5;
    int f4 = idx & 31;
    float d = dis[i];
    float d2 = d * d;
    float4 a = *(const float4*)(hW + (size_t)idx * 4);
    float4 b = *(const float4*)(bias + f4 * 4);
    float4 o;
    o.x = b.x + a.x * d2; o.y = b.y + a.y * d2;
    o.z = b.z + a.z * d2; o.w = b.w + a.w * d2;
    *(float4*)(agg + (size_t)idx * 4) = o;
}

// ---------- edge scatter: agg[row] += norm_e * hW[col], 1 wave per edge, 4 edges/wave ----------
__global__ __launch_bounds__(256) void k_scatter(const float* __restrict__ hW,
                                                 const int* __restrict__ rows,
                                                 const int* __restrict__ cols,
                                                 const float* __restrict__ ea,
                                                 const float* __restrict__ dis,
                                                 float* __restrict__ agg) {
    const int lane = threadIdx.x & 63;
    const int wid = (blockIdx.x * 256 + threadIdx.x) >> 6;
    const int f = lane * 2;
    int e0 = wid * 4;
#pragma unroll
    for (int j = 0; j < 4; ++j) {
        int e = e0 + j;
        if (e >= EE) return;
        int r = rows[e], c = cols[e];
        float nrm = dis[r] * ea[e] * dis[c];
        float2 v = *(const float2*)(hW + (size_t)c * HH + f);
        float* dst = agg + (size_t)r * HH + f;
        atomicAdd(dst, v.x * nrm);
        atomicAdd(dst + 1, v.y * nrm);
    }
}

// ---------- heads: logits = relu(h2@W1+b1)@w2+b2, plus mean/masked-max partials ----------
__global__ __launch_bounds__(256) void k_heads(const float* __restrict__ Hb,
                                               const float* __restrict__ W1,
                                               const float* __restrict__ b1,
                                               const float* __restrict__ w2v,
                                               const float* __restrict__ b2,
                                               const int* __restrict__ ready,
                                               float* __restrict__ logits,
                                               float* __restrict__ meansum,
                                               unsigned* __restrict__ maxenc,
                                               unsigned* __restrict__ lmaxenc, int n) {
    __shared__ float As[64][HH];
    __shared__ int rdy[64];
    const int t = threadIdx.x;
    const int rb = blockIdx.x * 64;
#pragma unroll
    for (int i = 0; i < 8; ++i) {
        int lin = i * 1024 + t * 4;
        int r = lin >> 7, k = lin & 127;
        float4 v = make_float4(0.f, 0.f, 0.f, 0.f);
        if (rb + r < n) {
            v = *(const float4*)(Hb + (size_t)(rb + r) * HH + k);
            v.x = fmaxf(v.x, 0.f); v.y = fmaxf(v.y, 0.f);
            v.z = fmaxf(v.z, 0.f); v.w = fmaxf(v.w, 0.f);
        }
        *(float4*)(&As[r][k]) = v;
    }
    if (t < 64) rdy[t] = (rb + t < n) ? ready[rb + t] : 0;
    __syncthreads();

    int lim = min(64, n - rb);
    if (t < HH) {  // per-feature tile sum (mean) and masked max
        float s = 0.f, mx = -3.4e38f;
        for (int r = 0; r < lim; ++r) {
            float v = As[r][t];
            s += v;
            if (rdy[r] > 0) mx = fmaxf(mx, v);
        }
        atomicAdd(&meansum[t], s);
        if (mx > -3.0e38f) atomicMax(&maxenc[t], encf(mx));
    }

    const int f0 = (t & 31) * 4;
    const int r0 = (t >> 5) * 8;
    float acc[8][4];
#pragma unroll
    for (int i = 0; i < 8; ++i)
#pragma unroll
        for (int c = 0; c < 4; ++c) acc[i][c] = 0.f;
    for (int k = 0; k < HH; k += 4) {
        float4 w0 = *(const float4*)(W1 + (size_t)(k + 0) * HH + f0);
        float4 w1 = *(const float4*)(W1 + (size_t)(k + 1) * HH + f0);
        float4 w2 = *(const float4*)(W1 + (size_t)(k + 2) * HH + f0);
        float4 w3 = *(const float4*)(W1 + (size_t)(k + 3) * HH + f0);
#pragma unroll
        for (int i = 0; i < 8; ++i) {
            float4 a = *(const float4*)(&As[r0 + i][k]);
            acc[i][0] += a.x * w0.x + a.y * w1.x + a.z * w2.x + a.w * w3.x;
            acc[i][1] += a.x * w0.y + a.y * w1.y + a.z * w2.y + a.w * w3.y;
            acc[i][2] += a.x * w0.z + a.y * w1.z + a.z * w2.z + a.w * w3.z;
            acc[i][3] += a.x * w0.w + a.y * w1.w + a.z * w2.w + a.w * w3.w;
        }
    }
    // epilogue: z = relu(acc + b1); logit partial = sum z*w2 ; reduce over 32-lane group
    const float b2s = b2[0];
    float lmax = -3.4e38f;
#pragma unroll
    for (int i = 0; i < 8; ++i) {
        int r = r0 + i;
        float s = 0.f;
#pragma unroll
        for (int c = 0; c < 4; ++c) {
            float z = fmaxf(acc[i][c] + b1[f0 + c], 0.f);
            s += z * w2v[f0 + c];
        }
#pragma unroll
        for (int off = 16; off > 0; off >>= 1) s += __shfl_xor(s, off, 32);
        if ((t & 31) == 0 && rb + r < n) {
            float lg = s + b2s;
            logits[rb + r] = lg;
            if (rdy[r] > 0) lmax = fmaxf(lmax, lg);
        }
    }
    if ((t & 31) == 0 && lmax > -3.0e38f) atomicMax(lmaxenc, encf(lmax));
}

// ---------- small finalize: fc, pass-MLP, v, global max M ----------
__global__ void k_fin1(const float* __restrict__ meansum, const unsigned* __restrict__ maxenc,
                       const unsigned* __restrict__ lmaxenc,
                       const float* __restrict__ val_w, const float* __restrict__ val_b,
                       const float* __restrict__ pe, const float* __restrict__ cl_w,
                       const float* __restrict__ cl_b, const float* __restrict__ pw1,
                       const float* __restrict__ pb1, const float* __restrict__ pw2,
                       const float* __restrict__ pb2, float* __restrict__ scal,
                       float* __restrict__ d_out) {
    __shared__ float xp[144];
    __shared__ float zp[HH];
    int t = threadIdx.x;
    if (t < HH) {
        xp[t] = decf(maxenc[t]);
    } else if (t < 144) {
        int c = t - HH;
        float s = cl_b[c];
        for (int k = 0; k < 30; ++k) s += pe[k] * cl_w[k * 16 + c];
        xp[t] = s;
    }
    __syncthreads();
    if (t < HH) {
        float s = pb1[t];
        for (int k = 0; k < 144; ++k) s += xp[k] * pw1[k * HH + t];
        zp[t] = fmaxf(s, 0.f);
    }
    __syncthreads();
    if (t < 64) {
        float s1 = zp[t] * pw2[t] + zp[t + 64] * pw2[t + 64];
        float s2 = meansum[t] * val_w[t] + meansum[t + 64] * val_w[t + 64];
#pragma unroll
        for (int off = 32; off > 0; off >>= 1) {
            s1 += __shfl_xor(s1, off, 64);
            s2 += __shfl_xor(s2, off, 64);
        }
        if (t == 0) {
            float xpass = s1 + pb2[0];
            float v = s2 * (1.0f / NN) + val_b[0];
            float M = fmaxf(decf(lmaxenc[0]), xpass);
            scal[0] = M;
            scal[1] = expf(xpass - M);
            d_out[NN + 1] = v;
        }
    }
}

// ---------- exp pass: unnormalized probs + sum ----------
__global__ __launch_bounds__(256) void k_exp(const float* __restrict__ logits,
                                             const int* __restrict__ ready,
                                             const float* __restrict__ scal,
                                             float* __restrict__ d_out,
                                             float* __restrict__ esum) {
    __shared__ float warr[4];
    int t = threadIdx.x;
    int i = blockIdx.x * 256 + t;
    float M = scal[0];
    float p = 0.f;
    if (i < NN) {
        if (ready[i] > 0) p = expf(logits[i] - M);
        d_out[i] = p;
    }
    float s = p;
#pragma unroll
    for (int off = 32; off > 0; off >>= 1) s += __shfl_xor(s, off, 64);
    if ((t & 63) == 0) warr[t >> 6] = s;
    __syncthreads();
    if (t == 0) atomicAdd(esum, warr[0] + warr[1] + warr[2] + warr[3]);
}

// ---------- normalize ----------
__global__ void k_scale(const float* __restrict__ esum, const float* __restrict__ scal,
                        float* __restrict__ d_out) {
    int i = blockIdx.x * blockDim.x + threadIdx.x;
    float inv = 1.0f / (esum[0] + scal[1]);
    if (i < NN) d_out[i] *= inv;
    else if (i == NN) d_out[NN] = scal[1] * inv;
}

extern "C" void kernel_launch(void* const* d_in, const int* in_sizes, int n_in,
                              void* d_out, int out_size, void* d_ws, size_t ws_size,
                              hipStream_t stream) {
    const float* x      = (const float*)d_in[0];
    const int*   edges  = (const int*)d_in[1];
    const float* eattr  = (const float*)d_in[2];
    const int*   ready  = (const int*)d_in[3];
    const float* pe     = (const float*)d_in[4];
    const float* gcn_w  = (const float*)d_in[5];
    const float* gcn_b  = (const float*)d_in[6];
    const float* mlp_w1 = (const float*)d_in[7];
    const float* mlp_b1 = (const float*)d_in[8];
    const float* mlp_w2 = (const float*)d_in[9];
    const float* mlp_b2 = (const float*)d_in[10];
    const float* val_w  = (const float*)d_in[11];
    const float* val_b  = (const float*)d_in[12];
    const float* cl_w   = (const float*)d_in[13];
    const float* cl_b   = (const float*)d_in[14];
    const float* pw1    = (const float*)d_in[15];
    const float* pb1    = (const float*)d_in[16];
    const float* pw2    = (const float*)d_in[17];
    const float* pb2    = (const float*)d_in[18];

    const int* rows = edges;
    const int* cols = edges + EE;

    // workspace layout (all fp32, 16B-aligned slices): ~104 MB
    float* ws      = (float*)d_ws;
    float* deg     = ws;                         // N
    float* dis     = ws + NN;                    // N
    float* logits  = ws + 2 * (size_t)NN;        // N
    float* bufA    = ws + 3 * (size_t)NN;        // N*128
    float* bufB    = bufA + (size_t)NN * HH;     // N*128
    float* meansum = bufB + (size_t)NN * HH;     // 128
    unsigned* maxenc  = (unsigned*)(meansum + HH);  // 128
    unsigned* lmaxenc = maxenc + HH;                // 1
    float* esum    = (float*)(lmaxenc + 1);      // 1
    float* scal    = esum + 1;                   // 2: [M, exp(x_pass-M)]

    float* out = (float*)d_out;

    const int nb  = (NN + 255) / 256;
    const int gb  = (NN + 63) / 64;                       // GEMM tiles
    const int sb  = (((EE + 3) / 4) + 3) / 4;             // scatter blocks (4 waves/blk, 4 edges/wave)
    const int eb  = (NN * 32 + 255) / 256;                // selfinit blocks

    k_init<<<nb, 256, 0, stream>>>(deg, meansum, maxenc, lmaxenc, esum);
    k_deg<<<(EE + 255) / 256, 256, 0, stream>>>(rows, eattr, deg);
    k_dis<<<nb, 256, 0, stream>>>(deg, dis);

    // layer 0
    k_gemm<false><<<gb, 256, 0, stream>>>(x, gcn_w, bufA, NN);
    k_selfinit<<<eb, 256, 0, stream>>>(bufA, dis, gcn_b, bufB);
    k_scatter<<<sb, 256, 0, stream>>>(bufA, rows, cols, eattr, dis, bufB);

    // layer 1 (relu applied on load of bufB)
    k_gemm<true><<<gb, 256, 0, stream>>>(bufB, gcn_w + 16384, bufA, NN);
    k_selfinit<<<eb, 256, 0, stream>>>(bufA, dis, gcn_b + HH, bufB);
    k_scatter<<<sb, 256, 0, stream>>>(bufA, rows, cols, eattr, dis, bufB);

    // heads
    k_heads<<<gb, 256, 0, stream>>>(bufB, mlp_w1, mlp_b1, mlp_w2, mlp_b2, ready,
                                    logits, meansum, maxenc, lmaxenc, NN);
    k_fin1<<<1, 256, 0, stream>>>(meansum, maxenc, lmaxenc, val_w, val_b, pe, cl_w, cl_b,
                                  pw1, pb1, pw2, pb2, scal, out);
    k_exp<<<nb, 256, 0, stream>>>(logits, ready, scal, out, esum);
    k_scale<<<(NN + 1 + 255) / 256, 256, 0, stream>>>(esum, scal, out);
}

// Round 2
// 851.793 us; speedup vs baseline: 3.5531x; 3.5531x over previous
//
#include <hip/hip_runtime.h>
#include <cstdint>

#define NN 100000
#define EE 1600000
#define HH 128
#define SCAN_CHUNK 512
#define NSCAN ((NN + SCAN_CHUNK - 1) / SCAN_CHUNK)   // 196

// ---------- monotone float<->uint encoding for atomicMax on floats ----------
__device__ __forceinline__ unsigned encf(float f) {
    int b = __float_as_int(f);
    return (b >= 0) ? ((unsigned)b | 0x80000000u) : ~(unsigned)b;
}
__device__ __forceinline__ float decf(unsigned u) {
    return (u & 0x80000000u) ? __int_as_float((int)(u & 0x7fffffffu))
                             : __int_as_float((int)(~u));
}
#define ENC_NEG_INF 0x007FFFFFu  // encf(-inf)

// ---------- init: deg=1 (self-loop weight), count=0, small accumulators ----------
__global__ void k_init(float* __restrict__ deg, int* __restrict__ count,
                       float* __restrict__ meansum,
                       unsigned* __restrict__ maxenc, unsigned* __restrict__ lmaxenc,
                       float* __restrict__ esum) {
    int i = blockIdx.x * blockDim.x + threadIdx.x;
    if (i < NN) { deg[i] = 1.0f; count[i] = 0; }
    if (i < HH) { meansum[i] = 0.f; maxenc[i] = ENC_NEG_INF; }
    if (i == 0) { lmaxenc[0] = ENC_NEG_INF; esum[0] = 0.f; }
}

// ---------- deg[i] += edge weights with row==i ; count[i]++ ----------
__global__ void k_deg(const int* __restrict__ rows, const float* __restrict__ ea,
                      float* __restrict__ deg, int* __restrict__ count) {
    int e = blockIdx.x * blockDim.x + threadIdx.x;
    if (e < EE) {
        int r = rows[e];
        atomicAdd(&deg[r], ea[e]);
        atomicAdd(&count[r], 1);
    }
}

__global__ void k_dis(const float* __restrict__ deg, float* __restrict__ dis) {
    int i = blockIdx.x * blockDim.x + threadIdx.x;
    if (i < NN) dis[i] = rsqrtf(deg[i]);  // deg >= 1 always (self-loop w=1, ea>=0)
}

// ---------- exclusive scan of count -> endp (3 kernels) ----------
__global__ void k_scan1(const int* __restrict__ cnt, int* __restrict__ out,
                        int* __restrict__ bsum) {
    int b = blockIdx.x, t = threadIdx.x;
    int i0 = b * SCAN_CHUNK + t * 2;
    int c0 = (i0 < NN) ? cnt[i0] : 0;
    int c1 = (i0 + 1 < NN) ? cnt[i0 + 1] : 0;
    int s = c0 + c1;
    int lane = t & 63, w = t >> 6;
    int v = s;
#pragma unroll
    for (int off = 1; off < 64; off <<= 1) {
        int u = __shfl_up(v, off, 64);
        if (lane >= off) v += u;
    }
    __shared__ int wsum[4];
    if (lane == 63) wsum[w] = v;
    __syncthreads();
    int wadd = 0;
    for (int j = 0; j < w; ++j) wadd += wsum[j];
    int incl = v + wadd;
    int excl = incl - s;
    if (i0 < NN) out[i0] = excl;
    if (i0 + 1 < NN) out[i0 + 1] = excl + c0;
    if (t == 255) bsum[b] = incl;
}

__global__ void k_scan2(int* __restrict__ bsum) {
    __shared__ int tmp[256];
    int t = threadIdx.x;
    int v = (t < NSCAN) ? bsum[t] : 0;
    tmp[t] = v;
    __syncthreads();
    for (int off = 1; off < 256; off <<= 1) {
        int u = (t >= off) ? tmp[t - off] : 0;
        __syncthreads();
        tmp[t] += u;
        __syncthreads();
    }
    if (t < NSCAN) bsum[t] = tmp[t] - v;  // exclusive
}

__global__ void k_scan3(int* __restrict__ out, const int* __restrict__ bsum) {
    int i = blockIdx.x * blockDim.x + threadIdx.x;
    if (i < NN) out[i] += bsum[i / SCAN_CHUNK];
}

// ---------- fill CSR: packed (col, norm) ; endp becomes inclusive scan ----------
__global__ void k_fill(const int* __restrict__ rows, const int* __restrict__ cols,
                       const float* __restrict__ ea, const float* __restrict__ dis,
                       int* __restrict__ endp, int2* __restrict__ csre) {
    int e = blockIdx.x * blockDim.x + threadIdx.x;
    if (e >= EE) return;
    int r = rows[e], c = cols[e];
    float w = dis[r] * ea[e] * dis[c];
    int slot = atomicAdd(&endp[r], 1);
    int2 p;
    p.x = c;
    p.y = __float_as_int(w);
    csre[slot] = p;
}

// ---------- gather aggregation: one wave per node, bias+self-loop folded in ----------
__global__ __launch_bounds__(256) void k_gather(const float* __restrict__ hW,
                                                const int2* __restrict__ csre,
                                                const int* __restrict__ endp,
                                                const float* __restrict__ dis,
                                                const float* __restrict__ bias,
                                                float* __restrict__ agg) {
    int node = (blockIdx.x * 256 + threadIdx.x) >> 6;
    if (node >= NN) return;
    int lane = threadIdx.x & 63;
    int f = lane * 2;
    int lo = (node == 0) ? 0 : endp[node - 1];
    int hi = endp[node];
    float d = dis[node];
    float d2 = d * d;
    float2 h = *(const float2*)(hW + (size_t)node * HH + f);
    float2 b = *(const float2*)(bias + f);
    float ax = b.x + h.x * d2;
    float ay = b.y + h.y * d2;
    int e = lo;
    for (; e + 1 < hi; e += 2) {
        int2 p0 = csre[e];
        int2 p1 = csre[e + 1];
        float2 v0 = *(const float2*)(hW + (size_t)p0.x * HH + f);
        float2 v1 = *(const float2*)(hW + (size_t)p1.x * HH + f);
        float w0 = __int_as_float(p0.y);
        float w1 = __int_as_float(p1.y);
        ax += w0 * v0.x + w1 * v1.x;
        ay += w0 * v0.y + w1 * v1.y;
    }
    if (e < hi) {
        int2 p0 = csre[e];
        float2 v0 = *(const float2*)(hW + (size_t)p0.x * HH + f);
        float w0 = __int_as_float(p0.y);
        ax += w0 * v0.x;
        ay += w0 * v0.y;
    }
    *(float2*)(agg + (size_t)node * HH + f) = make_float2(ax, ay);
}

// ---------- C[n,128] = (RELU?relu(A):A) @ W[128,128], fp32 VALU ----------
template <bool RELU>
__global__ __launch_bounds__(256) void k_gemm(const float* __restrict__ A,
                                              const float* __restrict__ W,
                                              float* __restrict__ C, int n) {
    __shared__ float As[64][HH];  // 32 KB
    const int t = threadIdx.x;
    const int rb = blockIdx.x * 64;
#pragma unroll
    for (int i = 0; i < 8; ++i) {
        int lin = i * 1024 + t * 4;
        int r = lin >> 7, k = lin & 127;
        float4 v = make_float4(0.f, 0.f, 0.f, 0.f);
        if (rb + r < n) {
            v = *(const float4*)(A + (size_t)(rb + r) * HH + k);
            if (RELU) {
                v.x = fmaxf(v.x, 0.f); v.y = fmaxf(v.y, 0.f);
                v.z = fmaxf(v.z, 0.f); v.w = fmaxf(v.w, 0.f);
            }
        }
        *(float4*)(&As[r][k]) = v;
    }
    __syncthreads();
    const int f0 = (t & 31) * 4;
    const int r0 = (t >> 5) * 8;
    float acc[8][4];
#pragma unroll
    for (int i = 0; i < 8; ++i)
#pragma unroll
        for (int c = 0; c < 4; ++c) acc[i][c] = 0.f;
    for (int k = 0; k < HH; k += 4) {
        float4 w0 = *(const float4*)(W + (size_t)(k + 0) * HH + f0);
        float4 w1 = *(const float4*)(W + (size_t)(k + 1) * HH + f0);
        float4 w2 = *(const float4*)(W + (size_t)(k + 2) * HH + f0);
        float4 w3 = *(const float4*)(W + (size_t)(k + 3) * HH + f0);
#pragma unroll
        for (int i = 0; i < 8; ++i) {
            float4 a = *(const float4*)(&As[r0 + i][k]);
            acc[i][0] += a.x * w0.x + a.y * w1.x + a.z * w2.x + a.w * w3.x;
            acc[i][1] += a.x * w0.y + a.y * w1.y + a.z * w2.y + a.w * w3.y;
            acc[i][2] += a.x * w0.z + a.y * w1.z + a.z * w2.z + a.w * w3.z;
            acc[i][3] += a.x * w0.w + a.y * w1.w + a.z * w2.w + a.w * w3.w;
        }
    }
#pragma unroll
    for (int i = 0; i < 8; ++i) {
        int r = rb + r0 + i;
        if (r < n)
            *(float4*)(C + (size_t)r * HH + f0) =
                make_float4(acc[i][0], acc[i][1], acc[i][2], acc[i][3]);
    }
}

// ---------- heads: logits = relu(h2@W1+b1)@w2+b2, plus mean/masked-max partials ----------
__global__ __launch_bounds__(256) void k_heads(const float* __restrict__ Hb,
                                               const float* __restrict__ W1,
                                               const float* __restrict__ b1,
                                               const float* __restrict__ w2v,
                                               const float* __restrict__ b2,
                                               const int* __restrict__ ready,
                                               float* __restrict__ logits,
                                               float* __restrict__ meansum,
                                               unsigned* __restrict__ maxenc,
                                               unsigned* __restrict__ lmaxenc, int n) {
    __shared__ float As[64][HH];
    __shared__ int rdy[64];
    const int t = threadIdx.x;
    const int rb = blockIdx.x * 64;
#pragma unroll
    for (int i = 0; i < 8; ++i) {
        int lin = i * 1024 + t * 4;
        int r = lin >> 7, k = lin & 127;
        float4 v = make_float4(0.f, 0.f, 0.f, 0.f);
        if (rb + r < n) {
            v = *(const float4*)(Hb + (size_t)(rb + r) * HH + k);
            v.x = fmaxf(v.x, 0.f); v.y = fmaxf(v.y, 0.f);
            v.z = fmaxf(v.z, 0.f); v.w = fmaxf(v.w, 0.f);
        }
        *(float4*)(&As[r][k]) = v;
    }
    if (t < 64) rdy[t] = (rb + t < n) ? ready[rb + t] : 0;
    __syncthreads();

    int lim = min(64, n - rb);
    if (t < HH) {
        float s = 0.f, mx = -3.4e38f;
        for (int r = 0; r < lim; ++r) {
            float v = As[r][t];
            s += v;
            if (rdy[r] > 0) mx = fmaxf(mx, v);
        }
        atomicAdd(&meansum[t], s);
        if (mx > -3.0e38f) atomicMax(&maxenc[t], encf(mx));
    }

    const int f0 = (t & 31) * 4;
    const int r0 = (t >> 5) * 8;
    float acc[8][4];
#pragma unroll
    for (int i = 0; i < 8; ++i)
#pragma unroll
        for (int c = 0; c < 4; ++c) acc[i][c] = 0.f;
    for (int k = 0; k < HH; k += 4) {
        float4 w0 = *(const float4*)(W1 + (size_t)(k + 0) * HH + f0);
        float4 w1 = *(const float4*)(W1 + (size_t)(k + 1) * HH + f0);
        float4 w2 = *(const float4*)(W1 + (size_t)(k + 2) * HH + f0);
        float4 w3 = *(const float4*)(W1 + (size_t)(k + 3) * HH + f0);
#pragma unroll
        for (int i = 0; i < 8; ++i) {
            float4 a = *(const float4*)(&As[r0 + i][k]);
            acc[i][0] += a.x * w0.x + a.y * w1.x + a.z * w2.x + a.w * w3.x;
            acc[i][1] += a.x * w0.y + a.y * w1.y + a.z * w2.y + a.w * w3.y;
            acc[i][2] += a.x * w0.z + a.y * w1.z + a.z * w2.z + a.w * w3.z;
            acc[i][3] += a.x * w0.w + a.y * w1.w + a.z * w2.w + a.w * w3.w;
        }
    }
    const float b2s = b2[0];
    float lmax = -3.4e38f;
#pragma unroll
    for (int i = 0; i < 8; ++i) {
        int r = r0 + i;
        float s = 0.f;
#pragma unroll
        for (int c = 0; c < 4; ++c) {
            float z = fmaxf(acc[i][c] + b1[f0 + c], 0.f);
            s += z * w2v[f0 + c];
        }
#pragma unroll
        for (int off = 16; off > 0; off >>= 1) s += __shfl_xor(s, off, 32);
        if ((t & 31) == 0 && rb + r < n) {
            float lg = s + b2s;
            logits[rb + r] = lg;
            if (rdy[r] > 0) lmax = fmaxf(lmax, lg);
        }
    }
    if ((t & 31) == 0 && lmax > -3.0e38f) atomicMax(lmaxenc, encf(lmax));
}

// ---------- small finalize: fc, pass-MLP, v, global max M ----------
__global__ void k_fin1(const float* __restrict__ meansum, const unsigned* __restrict__ maxenc,
                       const unsigned* __restrict__ lmaxenc,
                       const float* __restrict__ val_w, const float* __restrict__ val_b,
                       const float* __restrict__ pe, const float* __restrict__ cl_w,
                       const float* __restrict__ cl_b, const float* __restrict__ pw1,
                       const float* __restrict__ pb1, const float* __restrict__ pw2,
                       const float* __restrict__ pb2, float* __restrict__ scal,
                       float* __restrict__ d_out) {
    __shared__ float xp[144];
    __shared__ float zp[HH];
    int t = threadIdx.x;
    if (t < HH) {
        xp[t] = decf(maxenc[t]);
    } else if (t < 144) {
        int c = t - HH;
        float s = cl_b[c];
        for (int k = 0; k < 30; ++k) s += pe[k] * cl_w[k * 16 + c];
        xp[t] = s;
    }
    __syncthreads();
    if (t < HH) {
        float s = pb1[t];
        for (int k = 0; k < 144; ++k) s += xp[k] * pw1[k * HH + t];
        zp[t] = fmaxf(s, 0.f);
    }
    __syncthreads();
    if (t < 64) {
        float s1 = zp[t] * pw2[t] + zp[t + 64] * pw2[t + 64];
        float s2 = meansum[t] * val_w[t] + meansum[t + 64] * val_w[t + 64];
#pragma unroll
        for (int off = 32; off > 0; off >>= 1) {
            s1 += __shfl_xor(s1, off, 64);
            s2 += __shfl_xor(s2, off, 64);
        }
        if (t == 0) {
            float xpass = s1 + pb2[0];
            float v = s2 * (1.0f / NN) + val_b[0];
            float M = fmaxf(decf(lmaxenc[0]), xpass);
            scal[0] = M;
            scal[1] = expf(xpass - M);
            d_out[NN + 1] = v;
        }
    }
}

// ---------- exp pass: unnormalized probs + sum ----------
__global__ __launch_bounds__(256) void k_exp(const float* __restrict__ logits,
                                             const int* __restrict__ ready,
                                             const float* __restrict__ scal,
                                             float* __restrict__ d_out,
                                             float* __restrict__ esum) {
    __shared__ float warr[4];
    int t = threadIdx.x;
    int i = blockIdx.x * 256 + t;
    float M = scal[0];
    float p = 0.f;
    if (i < NN) {
        if (ready[i] > 0) p = expf(logits[i] - M);
        d_out[i] = p;
    }
    float s = p;
#pragma unroll
    for (int off = 32; off > 0; off >>= 1) s += __shfl_xor(s, off, 64);
    if ((t & 63) == 0) warr[t >> 6] = s;
    __syncthreads();
    if (t == 0) atomicAdd(esum, warr[0] + warr[1] + warr[2] + warr[3]);
}

// ---------- normalize ----------
__global__ void k_scale(const float* __restrict__ esum, const float* __restrict__ scal,
                        float* __restrict__ d_out) {
    int i = blockIdx.x * blockDim.x + threadIdx.x;
    float inv = 1.0f / (esum[0] + scal[1]);
    if (i < NN) d_out[i] *= inv;
    else if (i == NN) d_out[NN] = scal[1] * inv;
}

extern "C" void kernel_launch(void* const* d_in, const int* in_sizes, int n_in,
                              void* d_out, int out_size, void* d_ws, size_t ws_size,
                              hipStream_t stream) {
    const float* x      = (const float*)d_in[0];
    const int*   edges  = (const int*)d_in[1];
    const float* eattr  = (const float*)d_in[2];
    const int*   ready  = (const int*)d_in[3];
    const float* pe     = (const float*)d_in[4];
    const float* gcn_w  = (const float*)d_in[5];
    const float* gcn_b  = (const float*)d_in[6];
    const float* mlp_w1 = (const float*)d_in[7];
    const float* mlp_b1 = (const float*)d_in[8];
    const float* mlp_w2 = (const float*)d_in[9];
    const float* mlp_b2 = (const float*)d_in[10];
    const float* val_w  = (const float*)d_in[11];
    const float* val_b  = (const float*)d_in[12];
    const float* cl_w   = (const float*)d_in[13];
    const float* cl_b   = (const float*)d_in[14];
    const float* pw1    = (const float*)d_in[15];
    const float* pb1    = (const float*)d_in[16];
    const float* pw2    = (const float*)d_in[17];
    const float* pb2    = (const float*)d_in[18];

    const int* rows = edges;
    const int* cols = edges + EE;

    // workspace layout (~118 MB)
    float* ws      = (float*)d_ws;
    float* deg     = ws;                          // N
    float* dis     = ws + NN;                     // N
    float* logits  = ws + 2 * (size_t)NN;         // N
    float* bufA    = ws + 3 * (size_t)NN;         // N*128
    float* bufB    = bufA + (size_t)NN * HH;      // N*128
    int*   count   = (int*)(bufB + (size_t)NN * HH);  // N
    int*   endp    = count + NN;                  // N
    int*   bsum    = endp + NN;                   // 256
    int2*  csre    = (int2*)(bsum + 256);         // E (8B each)
    float* meansum = (float*)(csre + EE);         // 128
    unsigned* maxenc  = (unsigned*)(meansum + HH);
    unsigned* lmaxenc = maxenc + HH;
    float* esum    = (float*)(lmaxenc + 1);
    float* scal    = esum + 1;

    float* out = (float*)d_out;

    const int nb = (NN + 255) / 256;
    const int gb = (NN + 63) / 64;
    const int eb = (EE + 255) / 256;
    const int ab = (NN * 64 + 255) / 256;   // gather: wave per node

    k_init<<<nb, 256, 0, stream>>>(deg, count, meansum, maxenc, lmaxenc, esum);
    k_deg<<<eb, 256, 0, stream>>>(rows, eattr, deg, count);
    k_dis<<<nb, 256, 0, stream>>>(deg, dis);

    // CSR build
    k_scan1<<<NSCAN, 256, 0, stream>>>(count, endp, bsum);
    k_scan2<<<1, 256, 0, stream>>>(bsum);
    k_scan3<<<nb, 256, 0, stream>>>(endp, bsum);
    k_fill<<<eb, 256, 0, stream>>>(rows, cols, eattr, dis, endp, csre);

    // layer 0
    k_gemm<false><<<gb, 256, 0, stream>>>(x, gcn_w, bufA, NN);
    k_gather<<<ab, 256, 0, stream>>>(bufA, csre, endp, dis, gcn_b, bufB);

    // layer 1 (relu applied on load of bufB)
    k_gemm<true><<<gb, 256, 0, stream>>>(bufB, gcn_w + 16384, bufA, NN);
    k_gather<<<ab, 256, 0, stream>>>(bufA, csre, endp, dis, gcn_b + HH, bufB);

    // heads
    k_heads<<<gb, 256, 0, stream>>>(bufB, mlp_w1, mlp_b1, mlp_w2, mlp_b2, ready,
                                    logits, meansum, maxenc, lmaxenc, NN);
    k_fin1<<<1, 256, 0, stream>>>(meansum, maxenc, lmaxenc, val_w, val_b, pe, cl_w, cl_b,
                                  pw1, pb1, pw2, pb2, scal, out);
    k_exp<<<nb, 256, 0, stream>>>(logits, ready, scal, out, esum);
    k_scale<<<(NN + 1 + 255) / 256, 256, 0, stream>>>(esum, scal, out);
}

// Round 3
// 777.009 us; speedup vs baseline: 3.8951x; 1.0962x over previous
//
#include <hip/hip_runtime.h>
#include <cstdint>

#define NN 100000
#define EE 1600000
#define HH 128
#define NREP 8
#define SCAN_CHUNK 512
#define NSCAN ((NN + SCAN_CHUNK - 1) / SCAN_CHUNK)   // 196

typedef unsigned long long u64;

// ---------- monotone float<->uint encoding for atomicMax on floats ----------
__device__ __forceinline__ unsigned encf(float f) {
    int b = __float_as_int(f);
    return (b >= 0) ? ((unsigned)b | 0x80000000u) : ~(unsigned)b;
}
__device__ __forceinline__ float decf(unsigned u) {
    return (u & 0x80000000u) ? __int_as_float((int)(u & 0x7fffffffu))
                             : __int_as_float((int)(~u));
}
#define ENC_NEG_INF 0x007FFFFFu  // encf(-inf)

// ---------- init: zero replica histograms + small accumulators ----------
__global__ void k_init(u64* __restrict__ cnt64, float* __restrict__ meansum,
                       unsigned* __restrict__ maxenc, unsigned* __restrict__ lmaxenc,
                       float* __restrict__ esum) {
    int i = blockIdx.x * blockDim.x + threadIdx.x;
    if (i < NREP * NN) cnt64[i] = 0ull;
    if (i < HH) { meansum[i] = 0.f; maxenc[i] = ENC_NEG_INF; }
    if (i == 0) { lmaxenc[0] = ENC_NEG_INF; esum[0] = 0.f; }
}

// ---------- per-replica 64-bit packed histogram: count<<40 | fix30(weight) ----------
__global__ void k_deg(const int* __restrict__ rows, const float* __restrict__ ea,
                      u64* __restrict__ cnt64) {
    int e = blockIdx.x * blockDim.x + threadIdx.x;
    if (e >= EE) return;
    int rep = blockIdx.x & (NREP - 1);
    u64 pk = (1ull << 40) | (u64)(ea[e] * 1073741824.0f + 0.5f);
    atomicAdd(&cnt64[(size_t)rep * NN + rows[e]], pk);
}

// ---------- reduce replicas -> count, dis ----------
__global__ void k_red(const u64* __restrict__ cnt64, int* __restrict__ count,
                      float* __restrict__ dis) {
    int i = blockIdx.x * blockDim.x + threadIdx.x;
    if (i >= NN) return;
    u64 s = 0;
#pragma unroll
    for (int r = 0; r < NREP; ++r) s += cnt64[(size_t)r * NN + i];
    count[i] = (int)(s >> 40);
    float deg = 1.0f + (float)(s & ((1ull << 40) - 1)) * (1.0f / 1073741824.0f);
    dis[i] = rsqrtf(deg);
}

// ---------- exclusive scan of count -> base (3 kernels) ----------
__global__ void k_scan1(const int* __restrict__ cnt, int* __restrict__ out,
                        int* __restrict__ bsum) {
    int b = blockIdx.x, t = threadIdx.x;
    int i0 = b * SCAN_CHUNK + t * 2;
    int c0 = (i0 < NN) ? cnt[i0] : 0;
    int c1 = (i0 + 1 < NN) ? cnt[i0 + 1] : 0;
    int s = c0 + c1;
    int lane = t & 63, w = t >> 6;
    int v = s;
#pragma unroll
    for (int off = 1; off < 64; off <<= 1) {
        int u = __shfl_up(v, off, 64);
        if (lane >= off) v += u;
    }
    __shared__ int wsum[4];
    if (lane == 63) wsum[w] = v;
    __syncthreads();
    int wadd = 0;
    for (int j = 0; j < w; ++j) wadd += wsum[j];
    int incl = v + wadd;
    int excl = incl - s;
    if (i0 < NN) out[i0] = excl;
    if (i0 + 1 < NN) out[i0 + 1] = excl + c0;
    if (t == 255) bsum[b] = incl;
}

__global__ void k_scan2(int* __restrict__ bsum) {
    __shared__ int tmp[256];
    int t = threadIdx.x;
    int v = (t < NSCAN) ? bsum[t] : 0;
    tmp[t] = v;
    __syncthreads();
    for (int off = 1; off < 256; off <<= 1) {
        int u = (t >= off) ? tmp[t - off] : 0;
        __syncthreads();
        tmp[t] += u;
        __syncthreads();
    }
    if (t < NSCAN) bsum[t] = tmp[t] - v;  // exclusive
}

__global__ void k_scan3(int* __restrict__ out, const int* __restrict__ bsum) {
    int i = blockIdx.x * blockDim.x + threadIdx.x;
    if (i < NN) out[i] += bsum[i / SCAN_CHUNK];
}

// ---------- per-(replica,row) fill pointers + inclusive end ----------
__global__ void k_makeptr(const u64* __restrict__ cnt64, const int* __restrict__ base,
                          int* __restrict__ fillptr, int* __restrict__ endp) {
    int i = blockIdx.x * blockDim.x + threadIdx.x;
    if (i >= NN) return;
    int acc = base[i];
#pragma unroll
    for (int r = 0; r < NREP; ++r) {
        fillptr[(size_t)r * NN + i] = acc;
        acc += (int)(cnt64[(size_t)r * NN + i] >> 40);
    }
    endp[i] = acc;
}

// ---------- fill CSR: packed (col, norm) with replica-local slot atomics ----------
__global__ void k_fill(const int* __restrict__ rows, const int* __restrict__ cols,
                       const float* __restrict__ ea, const float* __restrict__ dis,
                       int* __restrict__ fillptr, int2* __restrict__ csre) {
    int e = blockIdx.x * blockDim.x + threadIdx.x;
    if (e >= EE) return;
    int rep = blockIdx.x & (NREP - 1);
    int r = rows[e], c = cols[e];
    float w = dis[r] * ea[e] * dis[c];
    int slot = atomicAdd(&fillptr[(size_t)rep * NN + r], 1);
    int2 p;
    p.x = c;
    p.y = __float_as_int(w);
    csre[slot] = p;
}

// ---------- gather aggregation: one wave per node, bias+self-loop folded in ----------
__global__ __launch_bounds__(256) void k_gather(const float* __restrict__ hW,
                                                const int2* __restrict__ csre,
                                                const int* __restrict__ base,
                                                const int* __restrict__ endp,
                                                const float* __restrict__ dis,
                                                const float* __restrict__ bias,
                                                float* __restrict__ agg) {
    int node = (blockIdx.x * 256 + threadIdx.x) >> 6;
    if (node >= NN) return;
    int lane = threadIdx.x & 63;
    int f = lane * 2;
    int lo = base[node];
    int hi = endp[node];
    float d = dis[node];
    float d2 = d * d;
    float2 h = *(const float2*)(hW + (size_t)node * HH + f);
    float2 b = *(const float2*)(bias + f);
    float ax = b.x + h.x * d2;
    float ay = b.y + h.y * d2;
    int e = lo;
    for (; e + 3 < hi; e += 4) {
        int2 p0 = csre[e];
        int2 p1 = csre[e + 1];
        int2 p2 = csre[e + 2];
        int2 p3 = csre[e + 3];
        float2 v0 = *(const float2*)(hW + (size_t)p0.x * HH + f);
        float2 v1 = *(const float2*)(hW + (size_t)p1.x * HH + f);
        float2 v2 = *(const float2*)(hW + (size_t)p2.x * HH + f);
        float2 v3 = *(const float2*)(hW + (size_t)p3.x * HH + f);
        float w0 = __int_as_float(p0.y), w1 = __int_as_float(p1.y);
        float w2 = __int_as_float(p2.y), w3 = __int_as_float(p3.y);
        ax += w0 * v0.x + w1 * v1.x + w2 * v2.x + w3 * v3.x;
        ay += w0 * v0.y + w1 * v1.y + w2 * v2.y + w3 * v3.y;
    }
    for (; e < hi; ++e) {
        int2 p0 = csre[e];
        float2 v0 = *(const float2*)(hW + (size_t)p0.x * HH + f);
        float w0 = __int_as_float(p0.y);
        ax += w0 * v0.x;
        ay += w0 * v0.y;
    }
    *(float2*)(agg + (size_t)node * HH + f) = make_float2(ax, ay);
}

// ---------- C[n,128] = (RELU?relu(A):A) @ W[128,128], fp32 VALU ----------
template <bool RELU>
__global__ __launch_bounds__(256) void k_gemm(const float* __restrict__ A,
                                              const float* __restrict__ W,
                                              float* __restrict__ C, int n) {
    __shared__ float As[64][HH];  // 32 KB
    const int t = threadIdx.x;
    const int rb = blockIdx.x * 64;
#pragma unroll
    for (int i = 0; i < 8; ++i) {
        int lin = i * 1024 + t * 4;
        int r = lin >> 7, k = lin & 127;
        float4 v = make_float4(0.f, 0.f, 0.f, 0.f);
        if (rb + r < n) {
            v = *(const float4*)(A + (size_t)(rb + r) * HH + k);
            if (RELU) {
                v.x = fmaxf(v.x, 0.f); v.y = fmaxf(v.y, 0.f);
                v.z = fmaxf(v.z, 0.f); v.w = fmaxf(v.w, 0.f);
            }
        }
        *(float4*)(&As[r][k]) = v;
    }
    __syncthreads();
    const int f0 = (t & 31) * 4;
    const int r0 = (t >> 5) * 8;
    float acc[8][4];
#pragma unroll
    for (int i = 0; i < 8; ++i)
#pragma unroll
        for (int c = 0; c < 4; ++c) acc[i][c] = 0.f;
    for (int k = 0; k < HH; k += 4) {
        float4 w0 = *(const float4*)(W + (size_t)(k + 0) * HH + f0);
        float4 w1 = *(const float4*)(W + (size_t)(k + 1) * HH + f0);
        float4 w2 = *(const float4*)(W + (size_t)(k + 2) * HH + f0);
        float4 w3 = *(const float4*)(W + (size_t)(k + 3) * HH + f0);
#pragma unroll
        for (int i = 0; i < 8; ++i) {
            float4 a = *(const float4*)(&As[r0 + i][k]);
            acc[i][0] += a.x * w0.x + a.y * w1.x + a.z * w2.x + a.w * w3.x;
            acc[i][1] += a.x * w0.y + a.y * w1.y + a.z * w2.y + a.w * w3.y;
            acc[i][2] += a.x * w0.z + a.y * w1.z + a.z * w2.z + a.w * w3.z;
            acc[i][3] += a.x * w0.w + a.y * w1.w + a.z * w2.w + a.w * w3.w;
        }
    }
#pragma unroll
    for (int i = 0; i < 8; ++i) {
        int r = rb + r0 + i;
        if (r < n)
            *(float4*)(C + (size_t)r * HH + f0) =
                make_float4(acc[i][0], acc[i][1], acc[i][2], acc[i][3]);
    }
}

// ---------- heads: logits = relu(h2@W1+b1)@w2+b2, plus mean/masked-max partials ----------
__global__ __launch_bounds__(256) void k_heads(const float* __restrict__ Hb,
                                               const float* __restrict__ W1,
                                               const float* __restrict__ b1,
                                               const float* __restrict__ w2v,
                                               const float* __restrict__ b2,
                                               const int* __restrict__ ready,
                                               float* __restrict__ logits,
                                               float* __restrict__ meansum,
                                               unsigned* __restrict__ maxenc,
                                               unsigned* __restrict__ lmaxenc, int n) {
    __shared__ float As[64][HH];
    __shared__ int rdy[64];
    const int t = threadIdx.x;
    const int rb = blockIdx.x * 64;
#pragma unroll
    for (int i = 0; i < 8; ++i) {
        int lin = i * 1024 + t * 4;
        int r = lin >> 7, k = lin & 127;
        float4 v = make_float4(0.f, 0.f, 0.f, 0.f);
        if (rb + r < n) {
            v = *(const float4*)(Hb + (size_t)(rb + r) * HH + k);
            v.x = fmaxf(v.x, 0.f); v.y = fmaxf(v.y, 0.f);
            v.z = fmaxf(v.z, 0.f); v.w = fmaxf(v.w, 0.f);
        }
        *(float4*)(&As[r][k]) = v;
    }
    if (t < 64) rdy[t] = (rb + t < n) ? ready[rb + t] : 0;
    __syncthreads();

    int lim = min(64, n - rb);
    if (t < HH) {
        float s = 0.f, mx = -3.4e38f;
        for (int r = 0; r < lim; ++r) {
            float v = As[r][t];
            s += v;
            if (rdy[r] > 0) mx = fmaxf(mx, v);
        }
        atomicAdd(&meansum[t], s);
        if (mx > -3.0e38f) atomicMax(&maxenc[t], encf(mx));
    }

    const int f0 = (t & 31) * 4;
    const int r0 = (t >> 5) * 8;
    float acc[8][4];
#pragma unroll
    for (int i = 0; i < 8; ++i)
#pragma unroll
        for (int c = 0; c < 4; ++c) acc[i][c] = 0.f;
    for (int k = 0; k < HH; k += 4) {
        float4 w0 = *(const float4*)(W1 + (size_t)(k + 0) * HH + f0);
        float4 w1 = *(const float4*)(W1 + (size_t)(k + 1) * HH + f0);
        float4 w2 = *(const float4*)(W1 + (size_t)(k + 2) * HH + f0);
        float4 w3 = *(const float4*)(W1 + (size_t)(k + 3) * HH + f0);
#pragma unroll
        for (int i = 0; i < 8; ++i) {
            float4 a = *(const float4*)(&As[r0 + i][k]);
            acc[i][0] += a.x * w0.x + a.y * w1.x + a.z * w2.x + a.w * w3.x;
            acc[i][1] += a.x * w0.y + a.y * w1.y + a.z * w2.y + a.w * w3.y;
            acc[i][2] += a.x * w0.z + a.y * w1.z + a.z * w2.z + a.w * w3.z;
            acc[i][3] += a.x * w0.w + a.y * w1.w + a.z * w2.w + a.w * w3.w;
        }
    }
    const float b2s = b2[0];
    float lmax = -3.4e38f;
#pragma unroll
    for (int i = 0; i < 8; ++i) {
        int r = r0 + i;
        float s = 0.f;
#pragma unroll
        for (int c = 0; c < 4; ++c) {
            float z = fmaxf(acc[i][c] + b1[f0 + c], 0.f);
            s += z * w2v[f0 + c];
        }
#pragma unroll
        for (int off = 16; off > 0; off >>= 1) s += __shfl_xor(s, off, 32);
        if ((t & 31) == 0 && rb + r < n) {
            float lg = s + b2s;
            logits[rb + r] = lg;
            if (rdy[r] > 0) lmax = fmaxf(lmax, lg);
        }
    }
    if ((t & 31) == 0 && lmax > -3.0e38f) atomicMax(lmaxenc, encf(lmax));
}

// ---------- small finalize: fc, pass-MLP, v, global max M ----------
__global__ void k_fin1(const float* __restrict__ meansum, const unsigned* __restrict__ maxenc,
                       const unsigned* __restrict__ lmaxenc,
                       const float* __restrict__ val_w, const float* __restrict__ val_b,
                       const float* __restrict__ pe, const float* __restrict__ cl_w,
                       const float* __restrict__ cl_b, const float* __restrict__ pw1,
                       const float* __restrict__ pb1, const float* __restrict__ pw2,
                       const float* __restrict__ pb2, float* __restrict__ scal,
                       float* __restrict__ d_out) {
    __shared__ float xp[144];
    __shared__ float zp[HH];
    int t = threadIdx.x;
    if (t < HH) {
        xp[t] = decf(maxenc[t]);
    } else if (t < 144) {
        int c = t - HH;
        float s = cl_b[c];
        for (int k = 0; k < 30; ++k) s += pe[k] * cl_w[k * 16 + c];
        xp[t] = s;
    }
    __syncthreads();
    if (t < HH) {
        float s = pb1[t];
        for (int k = 0; k < 144; ++k) s += xp[k] * pw1[k * HH + t];
        zp[t] = fmaxf(s, 0.f);
    }
    __syncthreads();
    if (t < 64) {
        float s1 = zp[t] * pw2[t] + zp[t + 64] * pw2[t + 64];
        float s2 = meansum[t] * val_w[t] + meansum[t + 64] * val_w[t + 64];
#pragma unroll
        for (int off = 32; off > 0; off >>= 1) {
            s1 += __shfl_xor(s1, off, 64);
            s2 += __shfl_xor(s2, off, 64);
        }
        if (t == 0) {
            float xpass = s1 + pb2[0];
            float v = s2 * (1.0f / NN) + val_b[0];
            float M = fmaxf(decf(lmaxenc[0]), xpass);
            scal[0] = M;
            scal[1] = expf(xpass - M);
            d_out[NN + 1] = v;
        }
    }
}

// ---------- exp pass: unnormalized probs + sum ----------
__global__ __launch_bounds__(256) void k_exp(const float* __restrict__ logits,
                                             const int* __restrict__ ready,
                                             const float* __restrict__ scal,
                                             float* __restrict__ d_out,
                                             float* __restrict__ esum) {
    __shared__ float warr[4];
    int t = threadIdx.x;
    int i = blockIdx.x * 256 + t;
    float M = scal[0];
    float p = 0.f;
    if (i < NN) {
        if (ready[i] > 0) p = expf(logits[i] - M);
        d_out[i] = p;
    }
    float s = p;
#pragma unroll
    for (int off = 32; off > 0; off >>= 1) s += __shfl_xor(s, off, 64);
    if ((t & 63) == 0) warr[t >> 6] = s;
    __syncthreads();
    if (t == 0) atomicAdd(esum, warr[0] + warr[1] + warr[2] + warr[3]);
}

// ---------- normalize ----------
__global__ void k_scale(const float* __restrict__ esum, const float* __restrict__ scal,
                        float* __restrict__ d_out) {
    int i = blockIdx.x * blockDim.x + threadIdx.x;
    float inv = 1.0f / (esum[0] + scal[1]);
    if (i < NN) d_out[i] *= inv;
    else if (i == NN) d_out[NN] = scal[1] * inv;
}

extern "C" void kernel_launch(void* const* d_in, const int* in_sizes, int n_in,
                              void* d_out, int out_size, void* d_ws, size_t ws_size,
                              hipStream_t stream) {
    const float* x      = (const float*)d_in[0];
    const int*   edges  = (const int*)d_in[1];
    const float* eattr  = (const float*)d_in[2];
    const int*   ready  = (const int*)d_in[3];
    const float* pe     = (const float*)d_in[4];
    const float* gcn_w  = (const float*)d_in[5];
    const float* gcn_b  = (const float*)d_in[6];
    const float* mlp_w1 = (const float*)d_in[7];
    const float* mlp_b1 = (const float*)d_in[8];
    const float* mlp_w2 = (const float*)d_in[9];
    const float* mlp_b2 = (const float*)d_in[10];
    const float* val_w  = (const float*)d_in[11];
    const float* val_b  = (const float*)d_in[12];
    const float* cl_w   = (const float*)d_in[13];
    const float* cl_b   = (const float*)d_in[14];
    const float* pw1    = (const float*)d_in[15];
    const float* pb1    = (const float*)d_in[16];
    const float* pw2    = (const float*)d_in[17];
    const float* pb2    = (const float*)d_in[18];

    const int* rows = edges;
    const int* cols = edges + EE;

    // workspace layout (~118 MB)
    float* ws      = (float*)d_ws;
    float* dis     = ws;                          // N
    float* logits  = ws + NN;                     // N
    int*   count   = (int*)(ws + 2 * (size_t)NN); // N
    int*   base    = count + NN;                  // N
    int*   endp    = base + NN;                   // N
    int*   bsum    = endp + NN;                   // 256
    float* bufA    = (float*)(bsum + 256);        // N*128
    float* bufB    = bufA + (size_t)NN * HH;      // N*128
    int2*  csre    = (int2*)(bufB + (size_t)NN * HH);  // E (8B each)
    float* meansum = (float*)(csre + EE);         // 128
    unsigned* maxenc  = (unsigned*)(meansum + HH);
    unsigned* lmaxenc = maxenc + HH;
    float* esum    = (float*)(lmaxenc + 1);
    float* scal    = esum + 1;

    // aliases (lifetime-disjoint):
    //  cnt64 (8N u64, used k_init..k_makeptr) aliases csre (written only by k_fill, later)
    //  fillptr (8N int, used k_makeptr..k_fill) aliases bufB (written first by gather0, later)
    u64* cnt64   = (u64*)csre;
    int* fillptr = (int*)bufB;

    float* out = (float*)d_out;

    const int nb = (NN + 255) / 256;
    const int gb = (NN + 63) / 64;
    const int eb = (EE + 255) / 256;
    const int ab = (NN * 64 + 255) / 256;   // gather: wave per node
    const int ib = (NREP * NN + 255) / 256;

    k_init<<<ib, 256, 0, stream>>>(cnt64, meansum, maxenc, lmaxenc, esum);
    k_deg<<<eb, 256, 0, stream>>>(rows, eattr, cnt64);
    k_red<<<nb, 256, 0, stream>>>(cnt64, count, dis);

    // CSR build
    k_scan1<<<NSCAN, 256, 0, stream>>>(count, base, bsum);
    k_scan2<<<1, 256, 0, stream>>>(bsum);
    k_scan3<<<nb, 256, 0, stream>>>(base, bsum);
    k_makeptr<<<nb, 256, 0, stream>>>(cnt64, base, fillptr, endp);
    k_fill<<<eb, 256, 0, stream>>>(rows, cols, eattr, dis, fillptr, csre);

    // layer 0
    k_gemm<false><<<gb, 256, 0, stream>>>(x, gcn_w, bufA, NN);
    k_gather<<<ab, 256, 0, stream>>>(bufA, csre, base, endp, dis, gcn_b, bufB);

    // layer 1 (relu applied on load of bufB)
    k_gemm<true><<<gb, 256, 0, stream>>>(bufB, gcn_w + 16384, bufA, NN);
    k_gather<<<ab, 256, 0, stream>>>(bufA, csre, base, endp, dis, gcn_b + HH, bufB);

    // heads
    k_heads<<<gb, 256, 0, stream>>>(bufB, mlp_w1, mlp_b1, mlp_w2, mlp_b2, ready,
                                    logits, meansum, maxenc, lmaxenc, NN);
    k_fin1<<<1, 256, 0, stream>>>(meansum, maxenc, lmaxenc, val_w, val_b, pe, cl_w, cl_b,
                                  pw1, pb1, pw2, pb2, scal, out);
    k_exp<<<nb, 256, 0, stream>>>(logits, ready, scal, out, esum);
    k_scale<<<(NN + 1 + 255) / 256, 256, 0, stream>>>(esum, scal, out);
}

// Round 4
// 677.289 us; speedup vs baseline: 4.4686x; 1.1472x over previous
//
#include <hip/hip_runtime.h>
#include <cstdint>

#define NN 100000
#define EE 1600000
#define HH 128
#define NREP 8
#define SCAN_CHUNK 512
#define NSCAN ((NN + SCAN_CHUNK - 1) / SCAN_CHUNK)   // 196

typedef unsigned long long u64;
typedef unsigned short ushort;

// ---------- bf16 helpers (RNE, finite values) ----------
__device__ __forceinline__ ushort f2bf(float x) {
    union { float f; unsigned u; } v; v.f = x;
    unsigned r = v.u + 0x7fffu + ((v.u >> 16) & 1u);
    return (ushort)(r >> 16);
}
__device__ __forceinline__ float bf2f(unsigned h16) {
    union { unsigned u; float f; } v; v.u = h16 << 16; return v.f;
}
__device__ __forceinline__ void unpack8(uint4 q, float* v) {
    v[0] = bf2f(q.x & 0xffffu); v[1] = bf2f(q.x >> 16);
    v[2] = bf2f(q.y & 0xffffu); v[3] = bf2f(q.y >> 16);
    v[4] = bf2f(q.z & 0xffffu); v[5] = bf2f(q.z >> 16);
    v[6] = bf2f(q.w & 0xffffu); v[7] = bf2f(q.w >> 16);
}

// ---------- monotone float<->uint encoding for atomicMax on floats ----------
__device__ __forceinline__ unsigned encf(float f) {
    int b = __float_as_int(f);
    return (b >= 0) ? ((unsigned)b | 0x80000000u) : ~(unsigned)b;
}
__device__ __forceinline__ float decf(unsigned u) {
    return (u & 0x80000000u) ? __int_as_float((int)(u & 0x7fffffffu))
                             : __int_as_float((int)(~u));
}
#define ENC_NEG_INF 0x007FFFFFu  // encf(-inf)

// ---------- init: zero replica histograms + small accumulators ----------
__global__ void k_init(u64* __restrict__ cnt64, float* __restrict__ meansum,
                       unsigned* __restrict__ maxenc, unsigned* __restrict__ lmaxenc,
                       float* __restrict__ esum) {
    int i = blockIdx.x * blockDim.x + threadIdx.x;
    if (i < NREP * NN) cnt64[i] = 0ull;
    if (i < HH) { meansum[i] = 0.f; maxenc[i] = ENC_NEG_INF; }
    if (i == 0) { lmaxenc[0] = ENC_NEG_INF; esum[0] = 0.f; }
}

// ---------- per-replica 64-bit packed histogram: count<<40 | fix30(weight) ----------
__global__ void k_deg(const int* __restrict__ rows, const float* __restrict__ ea,
                      u64* __restrict__ cnt64) {
    int e = blockIdx.x * blockDim.x + threadIdx.x;
    if (e >= EE) return;
    int rep = blockIdx.x & (NREP - 1);
    u64 pk = (1ull << 40) | (u64)(ea[e] * 1073741824.0f + 0.5f);
    atomicAdd(&cnt64[(size_t)rep * NN + rows[e]], pk);
}

// ---------- reduce replicas -> count, dis ----------
__global__ void k_red(const u64* __restrict__ cnt64, int* __restrict__ count,
                      float* __restrict__ dis) {
    int i = blockIdx.x * blockDim.x + threadIdx.x;
    if (i >= NN) return;
    u64 s = 0;
#pragma unroll
    for (int r = 0; r < NREP; ++r) s += cnt64[(size_t)r * NN + i];
    count[i] = (int)(s >> 40);
    float deg = 1.0f + (float)(s & ((1ull << 40) - 1)) * (1.0f / 1073741824.0f);
    dis[i] = rsqrtf(deg);
}

// ---------- exclusive scan of count -> base (3 kernels) ----------
__global__ void k_scan1(const int* __restrict__ cnt, int* __restrict__ out,
                        int* __restrict__ bsum) {
    int b = blockIdx.x, t = threadIdx.x;
    int i0 = b * SCAN_CHUNK + t * 2;
    int c0 = (i0 < NN) ? cnt[i0] : 0;
    int c1 = (i0 + 1 < NN) ? cnt[i0 + 1] : 0;
    int s = c0 + c1;
    int lane = t & 63, w = t >> 6;
    int v = s;
#pragma unroll
    for (int off = 1; off < 64; off <<= 1) {
        int u = __shfl_up(v, off, 64);
        if (lane >= off) v += u;
    }
    __shared__ int wsum[4];
    if (lane == 63) wsum[w] = v;
    __syncthreads();
    int wadd = 0;
    for (int j = 0; j < w; ++j) wadd += wsum[j];
    int incl = v + wadd;
    int excl = incl - s;
    if (i0 < NN) out[i0] = excl;
    if (i0 + 1 < NN) out[i0 + 1] = excl + c0;
    if (t == 255) bsum[b] = incl;
}

__global__ void k_scan2(int* __restrict__ bsum) {
    __shared__ int tmp[256];
    int t = threadIdx.x;
    int v = (t < NSCAN) ? bsum[t] : 0;
    tmp[t] = v;
    __syncthreads();
    for (int off = 1; off < 256; off <<= 1) {
        int u = (t >= off) ? tmp[t - off] : 0;
        __syncthreads();
        tmp[t] += u;
        __syncthreads();
    }
    if (t < NSCAN) bsum[t] = tmp[t] - v;  // exclusive
}

__global__ void k_scan3(int* __restrict__ out, const int* __restrict__ bsum) {
    int i = blockIdx.x * blockDim.x + threadIdx.x;
    if (i < NN) out[i] += bsum[i / SCAN_CHUNK];
}

// ---------- per-(replica,row) fill pointers + inclusive end ----------
__global__ void k_makeptr(const u64* __restrict__ cnt64, const int* __restrict__ base,
                          int* __restrict__ fillptr, int* __restrict__ endp) {
    int i = blockIdx.x * blockDim.x + threadIdx.x;
    if (i >= NN) return;
    int acc = base[i];
#pragma unroll
    for (int r = 0; r < NREP; ++r) {
        fillptr[(size_t)r * NN + i] = acc;
        acc += (int)(cnt64[(size_t)r * NN + i] >> 40);
    }
    endp[i] = acc;
}

// ---------- fill CSR: packed (col, norm) with replica-local slot atomics ----------
__global__ void k_fill(const int* __restrict__ rows, const int* __restrict__ cols,
                       const float* __restrict__ ea, const float* __restrict__ dis,
                       int* __restrict__ fillptr, int2* __restrict__ csre) {
    int e = blockIdx.x * blockDim.x + threadIdx.x;
    if (e >= EE) return;
    int rep = blockIdx.x & (NREP - 1);
    int r = rows[e], c = cols[e];
    float w = dis[r] * ea[e] * dis[c];
    int slot = atomicAdd(&fillptr[(size_t)rep * NN + r], 1);
    int2 p;
    p.x = c;
    p.y = __float_as_int(w);
    csre[slot] = p;
}

// ---------- gather: wave per node, 4 groups x 16 lanes; bf16 rows, fp32 accum ----------
__global__ __launch_bounds__(256) void k_gather(const ushort* __restrict__ hW,
                                                const int2* __restrict__ csre,
                                                const int* __restrict__ base,
                                                const int* __restrict__ endp,
                                                const float* __restrict__ dis,
                                                const float* __restrict__ bias,
                                                float* __restrict__ agg) {
    int node = (blockIdx.x * 256 + threadIdx.x) >> 6;
    if (node >= NN) return;
    int lane = threadIdx.x & 63;
    int g = lane >> 4, l = lane & 15;
    int f = l * 8;
    int lo = base[node], hi = endp[node];
    float acc[8];
#pragma unroll
    for (int j = 0; j < 8; ++j) acc[j] = 0.f;
    if (g == 0) {  // self-loop term
        float d = dis[node];
        float d2 = d * d;
        uint4 q = *(const uint4*)(hW + (size_t)node * HH + f);
        float v[8]; unpack8(q, v);
#pragma unroll
        for (int j = 0; j < 8; ++j) acc[j] = d2 * v[j];
    }
    for (int e = lo + g; e < hi; e += 4) {
        int2 p = csre[e];
        float w = __int_as_float(p.y);
        uint4 q = *(const uint4*)(hW + (size_t)p.x * HH + f);
        float v[8]; unpack8(q, v);
#pragma unroll
        for (int j = 0; j < 8; ++j) acc[j] += w * v[j];
    }
#pragma unroll
    for (int j = 0; j < 8; ++j) {
        acc[j] += __shfl_xor(acc[j], 16, 64);
        acc[j] += __shfl_xor(acc[j], 32, 64);
    }
    if (g == 0) {
        float4 b0 = *(const float4*)(bias + f);
        float4 b1 = *(const float4*)(bias + f + 4);
        float* dst = agg + (size_t)node * HH + f;
        *(float4*)dst = make_float4(acc[0] + b0.x, acc[1] + b0.y, acc[2] + b0.z, acc[3] + b0.w);
        *(float4*)(dst + 4) = make_float4(acc[4] + b1.x, acc[5] + b1.y, acc[6] + b1.z, acc[7] + b1.w);
    }
}

// ---------- C_bf16[n,128] = (RELU?relu(A):A) @ W[128,128], fp32 VALU ----------
template <bool RELU>
__global__ __launch_bounds__(256) void k_gemm(const float* __restrict__ A,
                                              const float* __restrict__ W,
                                              ushort* __restrict__ C, int n) {
    __shared__ float As[64][HH];  // 32 KB
    const int t = threadIdx.x;
    const int rb = blockIdx.x * 64;
#pragma unroll
    for (int i = 0; i < 8; ++i) {
        int lin = i * 1024 + t * 4;
        int r = lin >> 7, k = lin & 127;
        float4 v = make_float4(0.f, 0.f, 0.f, 0.f);
        if (rb + r < n) {
            v = *(const float4*)(A + (size_t)(rb + r) * HH + k);
            if (RELU) {
                v.x = fmaxf(v.x, 0.f); v.y = fmaxf(v.y, 0.f);
                v.z = fmaxf(v.z, 0.f); v.w = fmaxf(v.w, 0.f);
            }
        }
        *(float4*)(&As[r][k]) = v;
    }
    __syncthreads();
    const int f0 = (t & 31) * 4;
    const int r0 = (t >> 5) * 8;
    float acc[8][4];
#pragma unroll
    for (int i = 0; i < 8; ++i)
#pragma unroll
        for (int c = 0; c < 4; ++c) acc[i][c] = 0.f;
    for (int k = 0; k < HH; k += 4) {
        float4 w0 = *(const float4*)(W + (size_t)(k + 0) * HH + f0);
        float4 w1 = *(const float4*)(W + (size_t)(k + 1) * HH + f0);
        float4 w2 = *(const float4*)(W + (size_t)(k + 2) * HH + f0);
        float4 w3 = *(const float4*)(W + (size_t)(k + 3) * HH + f0);
#pragma unroll
        for (int i = 0; i < 8; ++i) {
            float4 a = *(const float4*)(&As[r0 + i][k]);
            acc[i][0] += a.x * w0.x + a.y * w1.x + a.z * w2.x + a.w * w3.x;
            acc[i][1] += a.x * w0.y + a.y * w1.y + a.z * w2.y + a.w * w3.y;
            acc[i][2] += a.x * w0.z + a.y * w1.z + a.z * w2.z + a.w * w3.z;
            acc[i][3] += a.x * w0.w + a.y * w1.w + a.z * w2.w + a.w * w3.w;
        }
    }
#pragma unroll
    for (int i = 0; i < 8; ++i) {
        int r = rb + r0 + i;
        if (r < n) {
            ushort4 o;
            o.x = f2bf(acc[i][0]); o.y = f2bf(acc[i][1]);
            o.z = f2bf(acc[i][2]); o.w = f2bf(acc[i][3]);
            *(ushort4*)(C + (size_t)r * HH + f0) = o;
        }
    }
}

// ---------- heads: logits = relu(h2@W1+b1)@w2+b2, plus mean/masked-max partials ----------
__global__ __launch_bounds__(256) void k_heads(const float* __restrict__ Hb,
                                               const float* __restrict__ W1,
                                               const float* __restrict__ b1,
                                               const float* __restrict__ w2v,
                                               const float* __restrict__ b2,
                                               const int* __restrict__ ready,
                                               float* __restrict__ logits,
                                               float* __restrict__ meansum,
                                               unsigned* __restrict__ maxenc,
                                               unsigned* __restrict__ lmaxenc, int n) {
    __shared__ float As[64][HH];
    __shared__ int rdy[64];
    const int t = threadIdx.x;
    const int rb = blockIdx.x * 64;
#pragma unroll
    for (int i = 0; i < 8; ++i) {
        int lin = i * 1024 + t * 4;
        int r = lin >> 7, k = lin & 127;
        float4 v = make_float4(0.f, 0.f, 0.f, 0.f);
        if (rb + r < n) {
            v = *(const float4*)(Hb + (size_t)(rb + r) * HH + k);
            v.x = fmaxf(v.x, 0.f); v.y = fmaxf(v.y, 0.f);
            v.z = fmaxf(v.z, 0.f); v.w = fmaxf(v.w, 0.f);
        }
        *(float4*)(&As[r][k]) = v;
    }
    if (t < 64) rdy[t] = (rb + t < n) ? ready[rb + t] : 0;
    __syncthreads();

    int lim = min(64, n - rb);
    if (t < HH) {
        float s = 0.f, mx = -3.4e38f;
        for (int r = 0; r < lim; ++r) {
            float v = As[r][t];
            s += v;
            if (rdy[r] > 0) mx = fmaxf(mx, v);
        }
        atomicAdd(&meansum[t], s);
        if (mx > -3.0e38f) atomicMax(&maxenc[t], encf(mx));
    }

    const int f0 = (t & 31) * 4;
    const int r0 = (t >> 5) * 8;
    float acc[8][4];
#pragma unroll
    for (int i = 0; i < 8; ++i)
#pragma unroll
        for (int c = 0; c < 4; ++c) acc[i][c] = 0.f;
    for (int k = 0; k < HH; k += 4) {
        float4 w0 = *(const float4*)(W1 + (size_t)(k + 0) * HH + f0);
        float4 w1 = *(const float4*)(W1 + (size_t)(k + 1) * HH + f0);
        float4 w2 = *(const float4*)(W1 + (size_t)(k + 2) * HH + f0);
        float4 w3 = *(const float4*)(W1 + (size_t)(k + 3) * HH + f0);
#pragma unroll
        for (int i = 0; i < 8; ++i) {
            float4 a = *(const float4*)(&As[r0 + i][k]);
            acc[i][0] += a.x * w0.x + a.y * w1.x + a.z * w2.x + a.w * w3.x;
            acc[i][1] += a.x * w0.y + a.y * w1.y + a.z * w2.y + a.w * w3.y;
            acc[i][2] += a.x * w0.z + a.y * w1.z + a.z * w2.z + a.w * w3.z;
            acc[i][3] += a.x * w0.w + a.y * w1.w + a.z * w2.w + a.w * w3.w;
        }
    }
    const float b2s = b2[0];
    float lmax = -3.4e38f;
#pragma unroll
    for (int i = 0; i < 8; ++i) {
        int r = r0 + i;
        float s = 0.f;
#pragma unroll
        for (int c = 0; c < 4; ++c) {
            float z = fmaxf(acc[i][c] + b1[f0 + c], 0.f);
            s += z * w2v[f0 + c];
        }
#pragma unroll
        for (int off = 16; off > 0; off >>= 1) s += __shfl_xor(s, off, 32);
        if ((t & 31) == 0 && rb + r < n) {
            float lg = s + b2s;
            logits[rb + r] = lg;
            if (rdy[r] > 0) lmax = fmaxf(lmax, lg);
        }
    }
    if ((t & 31) == 0 && lmax > -3.0e38f) atomicMax(lmaxenc, encf(lmax));
}

// ---------- small finalize: fc, pass-MLP, v, global max M ----------
__global__ void k_fin1(const float* __restrict__ meansum, const unsigned* __restrict__ maxenc,
                       const unsigned* __restrict__ lmaxenc,
                       const float* __restrict__ val_w, const float* __restrict__ val_b,
                       const float* __restrict__ pe, const float* __restrict__ cl_w,
                       const float* __restrict__ cl_b, const float* __restrict__ pw1,
                       const float* __restrict__ pb1, const float* __restrict__ pw2,
                       const float* __restrict__ pb2, float* __restrict__ scal,
                       float* __restrict__ d_out) {
    __shared__ float xp[144];
    __shared__ float zp[HH];
    int t = threadIdx.x;
    if (t < HH) {
        xp[t] = decf(maxenc[t]);
    } else if (t < 144) {
        int c = t - HH;
        float s = cl_b[c];
        for (int k = 0; k < 30; ++k) s += pe[k] * cl_w[k * 16 + c];
        xp[t] = s;
    }
    __syncthreads();
    if (t < HH) {
        float s = pb1[t];
        for (int k = 0; k < 144; ++k) s += xp[k] * pw1[k * HH + t];
        zp[t] = fmaxf(s, 0.f);
    }
    __syncthreads();
    if (t < 64) {
        float s1 = zp[t] * pw2[t] + zp[t + 64] * pw2[t + 64];
        float s2 = meansum[t] * val_w[t] + meansum[t + 64] * val_w[t + 64];
#pragma unroll
        for (int off = 32; off > 0; off >>= 1) {
            s1 += __shfl_xor(s1, off, 64);
            s2 += __shfl_xor(s2, off, 64);
        }
        if (t == 0) {
            float xpass = s1 + pb2[0];
            float v = s2 * (1.0f / NN) + val_b[0];
            float M = fmaxf(decf(lmaxenc[0]), xpass);
            scal[0] = M;
            scal[1] = expf(xpass - M);
            d_out[NN + 1] = v;
        }
    }
}

// ---------- exp pass: unnormalized probs + sum ----------
__global__ __launch_bounds__(256) void k_exp(const float* __restrict__ logits,
                                             const int* __restrict__ ready,
                                             const float* __restrict__ scal,
                                             float* __restrict__ d_out,
                                             float* __restrict__ esum) {
    __shared__ float warr[4];
    int t = threadIdx.x;
    int i = blockIdx.x * 256 + t;
    float M = scal[0];
    float p = 0.f;
    if (i < NN) {
        if (ready[i] > 0) p = expf(logits[i] - M);
        d_out[i] = p;
    }
    float s = p;
#pragma unroll
    for (int off = 32; off > 0; off >>= 1) s += __shfl_xor(s, off, 64);
    if ((t & 63) == 0) warr[t >> 6] = s;
    __syncthreads();
    if (t == 0) atomicAdd(esum, warr[0] + warr[1] + warr[2] + warr[3]);
}

// ---------- normalize ----------
__global__ void k_scale(const float* __restrict__ esum, const float* __restrict__ scal,
                        float* __restrict__ d_out) {
    int i = blockIdx.x * blockDim.x + threadIdx.x;
    float inv = 1.0f / (esum[0] + scal[1]);
    if (i < NN) d_out[i] *= inv;
    else if (i == NN) d_out[NN] = scal[1] * inv;
}

extern "C" void kernel_launch(void* const* d_in, const int* in_sizes, int n_in,
                              void* d_out, int out_size, void* d_ws, size_t ws_size,
                              hipStream_t stream) {
    const float* x      = (const float*)d_in[0];
    const int*   edges  = (const int*)d_in[1];
    const float* eattr  = (const float*)d_in[2];
    const int*   ready  = (const int*)d_in[3];
    const float* pe     = (const float*)d_in[4];
    const float* gcn_w  = (const float*)d_in[5];
    const float* gcn_b  = (const float*)d_in[6];
    const float* mlp_w1 = (const float*)d_in[7];
    const float* mlp_b1 = (const float*)d_in[8];
    const float* mlp_w2 = (const float*)d_in[9];
    const float* mlp_b2 = (const float*)d_in[10];
    const float* val_w  = (const float*)d_in[11];
    const float* val_b  = (const float*)d_in[12];
    const float* cl_w   = (const float*)d_in[13];
    const float* cl_b   = (const float*)d_in[14];
    const float* pw1    = (const float*)d_in[15];
    const float* pb1    = (const float*)d_in[16];
    const float* pw2    = (const float*)d_in[17];
    const float* pb2    = (const float*)d_in[18];

    const int* rows = edges;
    const int* cols = edges + EE;

    // workspace layout (~93 MB)
    float* ws      = (float*)d_ws;
    float* dis     = ws;                          // N
    float* logits  = ws + NN;                     // N
    int*   count   = (int*)(ws + 2 * (size_t)NN); // N
    int*   base    = count + NN;                  // N
    int*   endp    = base + NN;                   // N
    int*   bsum    = endp + NN;                   // 256
    float* bufB    = (float*)(bsum + 256);        // N*128 fp32 (gather out / gemm in)
    ushort* bufH   = (ushort*)(bufB + (size_t)NN * HH);  // N*128 bf16 (gemm out / gather in)
    int2*  csre    = (int2*)(bufH + (size_t)NN * HH);    // E (8B each)
    float* meansum = (float*)(csre + EE);         // 128
    unsigned* maxenc  = (unsigned*)(meansum + HH);
    unsigned* lmaxenc = maxenc + HH;
    float* esum    = (float*)(lmaxenc + 1);
    float* scal    = esum + 1;

    // aliases (lifetime-disjoint):
    //  cnt64 (8N u64, used k_init..k_makeptr) aliases csre (written only by k_fill, later)
    //  fillptr (8N int, used k_makeptr..k_fill) aliases bufB (written first by gather0, later)
    u64* cnt64   = (u64*)csre;
    int* fillptr = (int*)bufB;

    float* out = (float*)d_out;

    const int nb = (NN + 255) / 256;
    const int gb = (NN + 63) / 64;
    const int eb = (EE + 255) / 256;
    const int ab = (NN * 64 + 255) / 256;   // gather: wave per node
    const int ib = (NREP * NN + 255) / 256;

    k_init<<<ib, 256, 0, stream>>>(cnt64, meansum, maxenc, lmaxenc, esum);
    k_deg<<<eb, 256, 0, stream>>>(rows, eattr, cnt64);
    k_red<<<nb, 256, 0, stream>>>(cnt64, count, dis);

    // CSR build
    k_scan1<<<NSCAN, 256, 0, stream>>>(count, base, bsum);
    k_scan2<<<1, 256, 0, stream>>>(bsum);
    k_scan3<<<nb, 256, 0, stream>>>(base, bsum);
    k_makeptr<<<nb, 256, 0, stream>>>(cnt64, base, fillptr, endp);
    k_fill<<<eb, 256, 0, stream>>>(rows, cols, eattr, dis, fillptr, csre);

    // layer 0
    k_gemm<false><<<gb, 256, 0, stream>>>(x, gcn_w, bufH, NN);
    k_gather<<<ab, 256, 0, stream>>>(bufH, csre, base, endp, dis, gcn_b, bufB);

    // layer 1 (relu applied on load of bufB)
    k_gemm<true><<<gb, 256, 0, stream>>>(bufB, gcn_w + 16384, bufH, NN);
    k_gather<<<ab, 256, 0, stream>>>(bufH, csre, base, endp, dis, gcn_b + HH, bufB);

    // heads
    k_heads<<<gb, 256, 0, stream>>>(bufB, mlp_w1, mlp_b1, mlp_w2, mlp_b2, ready,
                                    logits, meansum, maxenc, lmaxenc, NN);
    k_fin1<<<1, 256, 0, stream>>>(meansum, maxenc, lmaxenc, val_w, val_b, pe, cl_w, cl_b,
                                  pw1, pb1, pw2, pb2, scal, out);
    k_exp<<<nb, 256, 0, stream>>>(logits, ready, scal, out, esum);
    k_scale<<<(NN + 1 + 255) / 256, 256, 0, stream>>>(esum, scal, out);
}

// Round 5
// 577.569 us; speedup vs baseline: 5.2401x; 1.1727x over previous
//
#include <hip/hip_runtime.h>
#include <cstdint>

#define NN 100000
#define EE 1600000
#define HH 128
#define NREP 8
#define SCAN_CHUNK 512
#define NSCAN ((NN + SCAN_CHUNK - 1) / SCAN_CHUNK)   // 196

typedef unsigned long long u64;
typedef unsigned short ushort;
typedef __attribute__((ext_vector_type(8))) short bf16x8;
typedef __attribute__((ext_vector_type(4))) float f32x4;

// ---------- bf16 helpers (RNE, finite values) ----------
__device__ __forceinline__ ushort f2bf(float x) {
    union { float f; unsigned u; } v; v.f = x;
    unsigned r = v.u + 0x7fffu + ((v.u >> 16) & 1u);
    return (ushort)(r >> 16);
}
__device__ __forceinline__ float bf2f(unsigned h16) {
    union { unsigned u; float f; } v; v.u = h16 << 16; return v.f;
}
__device__ __forceinline__ void unpack8(uint4 q, float* v) {
    v[0] = bf2f(q.x & 0xffffu); v[1] = bf2f(q.x >> 16);
    v[2] = bf2f(q.y & 0xffffu); v[3] = bf2f(q.y >> 16);
    v[4] = bf2f(q.z & 0xffffu); v[5] = bf2f(q.z >> 16);
    v[6] = bf2f(q.w & 0xffffu); v[7] = bf2f(q.w >> 16);
}

// ---------- monotone float<->uint encoding for atomicMax on floats ----------
__device__ __forceinline__ unsigned encf(float f) {
    int b = __float_as_int(f);
    return (b >= 0) ? ((unsigned)b | 0x80000000u) : ~(unsigned)b;
}
__device__ __forceinline__ float decf(unsigned u) {
    return (u & 0x80000000u) ? __int_as_float((int)(u & 0x7fffffffu))
                             : __int_as_float((int)(~u));
}
#define ENC_NEG_INF 0x007FFFFFu  // encf(-inf)

// ---------- init: zero replica histograms + small accumulators ----------
__global__ void k_init(u64* __restrict__ cnt64, float* __restrict__ meansum,
                       unsigned* __restrict__ maxenc, unsigned* __restrict__ lmaxenc,
                       float* __restrict__ esum) {
    int i = blockIdx.x * blockDim.x + threadIdx.x;
    if (i < NREP * NN) cnt64[i] = 0ull;
    if (i < NREP * HH) { meansum[i] = 0.f; maxenc[i] = ENC_NEG_INF; }
    if (i == 0) { lmaxenc[0] = ENC_NEG_INF; esum[0] = 0.f; }
}

// ---------- pre-transpose weights to bf16 Wt[n][k] ----------
__global__ void k_prep(const float* __restrict__ w0, const float* __restrict__ w1,
                       const float* __restrict__ w2, ushort* __restrict__ wt) {
    int idx = blockIdx.x * blockDim.x + threadIdx.x;
    if (idx >= 3 * HH * HH) return;
    int mat = idx >> 14;          // /16384
    int e = idx & 16383;
    int n = e >> 7, k = e & 127;
    const float* src = (mat == 0) ? w0 : (mat == 1) ? w1 : w2;
    wt[idx] = f2bf(src[k * HH + n]);
}

// ---------- per-replica 64-bit packed histogram: count<<40 | fix30(weight) ----------
__global__ void k_deg(const int* __restrict__ rows, const float* __restrict__ ea,
                      u64* __restrict__ cnt64) {
    int e = blockIdx.x * blockDim.x + threadIdx.x;
    if (e >= EE) return;
    int rep = blockIdx.x & (NREP - 1);
    u64 pk = (1ull << 40) | (u64)(ea[e] * 1073741824.0f + 0.5f);
    atomicAdd(&cnt64[(size_t)rep * NN + rows[e]], pk);
}

// ---------- reduce replicas -> count, dis ----------
__global__ void k_red(const u64* __restrict__ cnt64, int* __restrict__ count,
                      float* __restrict__ dis) {
    int i = blockIdx.x * blockDim.x + threadIdx.x;
    if (i >= NN) return;
    u64 s = 0;
#pragma unroll
    for (int r = 0; r < NREP; ++r) s += cnt64[(size_t)r * NN + i];
    count[i] = (int)(s >> 40);
    float deg = 1.0f + (float)(s & ((1ull << 40) - 1)) * (1.0f / 1073741824.0f);
    dis[i] = rsqrtf(deg);
}

// ---------- exclusive scan of count -> base (3 kernels) ----------
__global__ void k_scan1(const int* __restrict__ cnt, int* __restrict__ out,
                        int* __restrict__ bsum) {
    int b = blockIdx.x, t = threadIdx.x;
    int i0 = b * SCAN_CHUNK + t * 2;
    int c0 = (i0 < NN) ? cnt[i0] : 0;
    int c1 = (i0 + 1 < NN) ? cnt[i0 + 1] : 0;
    int s = c0 + c1;
    int lane = t & 63, w = t >> 6;
    int v = s;
#pragma unroll
    for (int off = 1; off < 64; off <<= 1) {
        int u = __shfl_up(v, off, 64);
        if (lane >= off) v += u;
    }
    __shared__ int wsum[4];
    if (lane == 63) wsum[w] = v;
    __syncthreads();
    int wadd = 0;
    for (int j = 0; j < w; ++j) wadd += wsum[j];
    int incl = v + wadd;
    int excl = incl - s;
    if (i0 < NN) out[i0] = excl;
    if (i0 + 1 < NN) out[i0 + 1] = excl + c0;
    if (t == 255) bsum[b] = incl;
}

__global__ void k_scan2(int* __restrict__ bsum) {
    __shared__ int tmp[256];
    int t = threadIdx.x;
    int v = (t < NSCAN) ? bsum[t] : 0;
    tmp[t] = v;
    __syncthreads();
    for (int off = 1; off < 256; off <<= 1) {
        int u = (t >= off) ? tmp[t - off] : 0;
        __syncthreads();
        tmp[t] += u;
        __syncthreads();
    }
    if (t < NSCAN) bsum[t] = tmp[t] - v;  // exclusive
}

__global__ void k_scan3(int* __restrict__ out, const int* __restrict__ bsum) {
    int i = blockIdx.x * blockDim.x + threadIdx.x;
    if (i < NN) out[i] += bsum[i / SCAN_CHUNK];
}

// ---------- per-(replica,row) fill pointers + inclusive end ----------
__global__ void k_makeptr(const u64* __restrict__ cnt64, const int* __restrict__ base,
                          int* __restrict__ fillptr, int* __restrict__ endp) {
    int i = blockIdx.x * blockDim.x + threadIdx.x;
    if (i >= NN) return;
    int acc = base[i];
#pragma unroll
    for (int r = 0; r < NREP; ++r) {
        fillptr[(size_t)r * NN + i] = acc;
        acc += (int)(cnt64[(size_t)r * NN + i] >> 40);
    }
    endp[i] = acc;
}

// ---------- fill CSR: packed (col, norm) with replica-local slot atomics ----------
__global__ void k_fill(const int* __restrict__ rows, const int* __restrict__ cols,
                       const float* __restrict__ ea, const float* __restrict__ dis,
                       int* __restrict__ fillptr, int2* __restrict__ csre) {
    int e = blockIdx.x * blockDim.x + threadIdx.x;
    if (e >= EE) return;
    int rep = blockIdx.x & (NREP - 1);
    int r = rows[e], c = cols[e];
    float w = dis[r] * ea[e] * dis[c];
    int slot = atomicAdd(&fillptr[(size_t)rep * NN + r], 1);
    int2 p;
    p.x = c;
    p.y = __float_as_int(w);
    csre[slot] = p;
}

// ---------- gather: wave per node, 4 groups x 16 lanes; bf16 rows, fp32 accum ----------
__global__ __launch_bounds__(256) void k_gather(const ushort* __restrict__ hW,
                                                const int2* __restrict__ csre,
                                                const int* __restrict__ base,
                                                const int* __restrict__ endp,
                                                const float* __restrict__ dis,
                                                const float* __restrict__ bias,
                                                float* __restrict__ agg) {
    int node = (blockIdx.x * 256 + threadIdx.x) >> 6;
    if (node >= NN) return;
    int lane = threadIdx.x & 63;
    int g = lane >> 4, l = lane & 15;
    int f = l * 8;
    int lo = base[node], hi = endp[node];
    float acc[8];
#pragma unroll
    for (int j = 0; j < 8; ++j) acc[j] = 0.f;
    if (g == 0) {  // self-loop term
        float d = dis[node];
        float d2 = d * d;
        uint4 q = *(const uint4*)(hW + (size_t)node * HH + f);
        float v[8]; unpack8(q, v);
#pragma unroll
        for (int j = 0; j < 8; ++j) acc[j] = d2 * v[j];
    }
    for (int e = lo + g; e < hi; e += 4) {
        int2 p = csre[e];
        float w = __int_as_float(p.y);
        uint4 q = *(const uint4*)(hW + (size_t)p.x * HH + f);
        float v[8]; unpack8(q, v);
#pragma unroll
        for (int j = 0; j < 8; ++j) acc[j] += w * v[j];
    }
#pragma unroll
    for (int j = 0; j < 8; ++j) {
        acc[j] += __shfl_xor(acc[j], 16, 64);
        acc[j] += __shfl_xor(acc[j], 32, 64);
    }
    if (g == 0) {
        float4 b0 = *(const float4*)(bias + f);
        float4 b1 = *(const float4*)(bias + f + 4);
        float* dst = agg + (size_t)node * HH + f;
        *(float4*)dst = make_float4(acc[0] + b0.x, acc[1] + b0.y, acc[2] + b0.z, acc[3] + b0.w);
        *(float4*)(dst + 4) = make_float4(acc[4] + b1.x, acc[5] + b1.y, acc[6] + b1.z, acc[7] + b1.w);
    }
}

// ---------- MFMA GEMM: 64x128 tile, K=128, bf16 inputs, fp32 acc ----------
// MODE 0: C_bf16 = A @ W            (A fp32, no relu)
// MODE 1: C_bf16 = relu(A) @ W
// MODE 2: heads: logits = relu(relu(A)@W1 + b1) @ w2 + b2, plus mean/masked-max of relu(A)
template <int MODE>
__global__ __launch_bounds__(256) void k_mfma(const float* __restrict__ A,
                                              const ushort* __restrict__ Wt,
                                              ushort* __restrict__ C,
                                              const float* __restrict__ b1,
                                              const float* __restrict__ w2v,
                                              const float* __restrict__ b2,
                                              const int* __restrict__ ready,
                                              float* __restrict__ logits,
                                              float* __restrict__ meansum,
                                              unsigned* __restrict__ maxenc,
                                              unsigned* __restrict__ lmaxenc, int n) {
    __shared__ ushort As[64 * HH];   // 16 KB, swizzled: elem(m,k) at m*128 + ((k>>3)^(m&15))*8 + (k&7)
    __shared__ int rdy[64];
    __shared__ unsigned slmax;
    const int t = threadIdx.x;
    const int rb = blockIdx.x * 64;
    if (MODE == 2) {
        if (t < 64) rdy[t] = (rb + t < n) ? ready[rb + t] : 0;
        if (t == 0) slmax = ENC_NEG_INF;
    }
    // stage A tile (bf16, swizzled)
#pragma unroll
    for (int i = 0; i < 4; ++i) {
        int m = i * 16 + (t >> 4);
        int k = (t & 15) * 8;
        float4 v0 = make_float4(0.f, 0.f, 0.f, 0.f), v1 = v0;
        if (rb + m < n) {
            const float* src = A + (size_t)(rb + m) * HH + k;
            v0 = *(const float4*)src;
            v1 = *(const float4*)(src + 4);
            if (MODE >= 1) {
                v0.x = fmaxf(v0.x, 0.f); v0.y = fmaxf(v0.y, 0.f);
                v0.z = fmaxf(v0.z, 0.f); v0.w = fmaxf(v0.w, 0.f);
                v1.x = fmaxf(v1.x, 0.f); v1.y = fmaxf(v1.y, 0.f);
                v1.z = fmaxf(v1.z, 0.f); v1.w = fmaxf(v1.w, 0.f);
            }
        }
        ushort pk[8];
        pk[0] = f2bf(v0.x); pk[1] = f2bf(v0.y); pk[2] = f2bf(v0.z); pk[3] = f2bf(v0.w);
        pk[4] = f2bf(v1.x); pk[5] = f2bf(v1.y); pk[6] = f2bf(v1.z); pk[7] = f2bf(v1.w);
        int gsw = (t & 15) ^ (m & 15);
        *(uint4*)(As + m * HH + gsw * 8) = *(uint4*)pk;
    }
    __syncthreads();

    const int wave = t >> 6, lane = t & 63;
    const int cl = lane & 15;       // column-within-tile / A row
    const int kq = lane >> 4;       // k quad
    const int m0 = wave * 16;

    f32x4 acc[8];
#pragma unroll
    for (int c = 0; c < 8; ++c) acc[c] = (f32x4){0.f, 0.f, 0.f, 0.f};

    const int am = m0 + cl;
#pragma unroll
    for (int kk = 0; kk < 4; ++kk) {
        int g = kk * 4 + kq;
        bf16x8 a = *(const bf16x8*)(As + am * HH + ((g ^ cl) * 8));
#pragma unroll
        for (int c = 0; c < 8; ++c) {
            bf16x8 b = *(const bf16x8*)(Wt + (size_t)(c * 16 + cl) * HH + kk * 32 + kq * 8);
            acc[c] = __builtin_amdgcn_mfma_f32_16x16x32_bf16(a, b, acc[c], 0, 0, 0);
        }
    }

    if (MODE < 2) {
        // store C bf16: D row = m0 + kq*4 + r, col = c*16 + cl
#pragma unroll
        for (int c = 0; c < 8; ++c) {
#pragma unroll
            for (int r = 0; r < 4; ++r) {
                int row = rb + m0 + kq * 4 + r;
                if (row < n) C[(size_t)row * HH + c * 16 + cl] = f2bf(acc[c][r]);
            }
        }
    } else {
        // heads epilogue
        float b1c[8], w2c[8];
#pragma unroll
        for (int c = 0; c < 8; ++c) { b1c[c] = b1[c * 16 + cl]; w2c[c] = w2v[c * 16 + cl]; }
        const float b2s = b2[0];
        unsigned mylmax = ENC_NEG_INF;
#pragma unroll
        for (int r = 0; r < 4; ++r) {
            float s = 0.f;
#pragma unroll
            for (int c = 0; c < 8; ++c)
                s += fmaxf(acc[c][r] + b1c[c], 0.f) * w2c[c];
            s += __shfl_xor(s, 1, 64);
            s += __shfl_xor(s, 2, 64);
            s += __shfl_xor(s, 4, 64);
            s += __shfl_xor(s, 8, 64);
            if (cl == 0) {
                int rloc = m0 + kq * 4 + r;
                int row = rb + rloc;
                if (row < n) {
                    float lg = s + b2s;
                    logits[row] = lg;
                    if (rdy[rloc] > 0) {
                        unsigned e = encf(lg);
                        if (e > mylmax) mylmax = e;
                    }
                }
            }
        }
        if (cl == 0 && mylmax != ENC_NEG_INF) atomicMax(&slmax, mylmax);

        // mean / masked-max of h = relu(A) (bf16 tile), per feature
        int lim = min(64, n - rb);
        if (t < HH) {
            int f = t, gf = f >> 3, fo = f & 7;
            float sum = 0.f, mx = -3.4e38f;
            for (int m = 0; m < lim; ++m) {
                float v = bf2f(As[m * HH + ((gf ^ (m & 15)) * 8) + fo]);
                sum += v;
                if (rdy[m] > 0) mx = fmaxf(mx, v);
            }
            int rep = blockIdx.x & (NREP - 1);
            atomicAdd(&meansum[rep * HH + f], sum);
            if (mx > -3.0e38f) atomicMax(&maxenc[rep * HH + f], encf(mx));
        }
        __syncthreads();
        if (t == 0 && slmax != ENC_NEG_INF) atomicMax(lmaxenc, slmax);
    }
}

// ---------- small finalize: fc, pass-MLP, v, global max M ----------
__global__ void k_fin1(const float* __restrict__ meansum, const unsigned* __restrict__ maxenc,
                       const unsigned* __restrict__ lmaxenc,
                       const float* __restrict__ val_w, const float* __restrict__ val_b,
                       const float* __restrict__ pe, const float* __restrict__ cl_w,
                       const float* __restrict__ cl_b, const float* __restrict__ pw1,
                       const float* __restrict__ pb1, const float* __restrict__ pw2,
                       const float* __restrict__ pb2, float* __restrict__ scal,
                       float* __restrict__ d_out) {
    __shared__ float xp[144];
    __shared__ float msum[HH];
    __shared__ float zp[HH];
    int t = threadIdx.x;
    if (t < HH) {
        float s = 0.f;
        unsigned mx = ENC_NEG_INF;
#pragma unroll
        for (int r = 0; r < NREP; ++r) {
            s += meansum[r * HH + t];
            unsigned e = maxenc[r * HH + t];
            if (e > mx) mx = e;
        }
        msum[t] = s;
        xp[t] = decf(mx);
    } else if (t < 144) {
        int c = t - HH;
        float s = cl_b[c];
        for (int k = 0; k < 30; ++k) s += pe[k] * cl_w[k * 16 + c];
        xp[t] = s;
    }
    __syncthreads();
    if (t < HH) {
        float s = pb1[t];
        for (int k = 0; k < 144; ++k) s += xp[k] * pw1[k * HH + t];
        zp[t] = fmaxf(s, 0.f);
    }
    __syncthreads();
    if (t < 64) {
        float s1 = zp[t] * pw2[t] + zp[t + 64] * pw2[t + 64];
        float s2 = msum[t] * val_w[t] + msum[t + 64] * val_w[t + 64];
#pragma unroll
        for (int off = 32; off > 0; off >>= 1) {
            s1 += __shfl_xor(s1, off, 64);
            s2 += __shfl_xor(s2, off, 64);
        }
        if (t == 0) {
            float xpass = s1 + pb2[0];
            float v = s2 * (1.0f / NN) + val_b[0];
            float M = fmaxf(decf(lmaxenc[0]), xpass);
            scal[0] = M;
            scal[1] = expf(xpass - M);
            d_out[NN + 1] = v;
        }
    }
}

// ---------- exp pass: unnormalized probs + sum ----------
__global__ __launch_bounds__(256) void k_exp(const float* __restrict__ logits,
                                             const int* __restrict__ ready,
                                             const float* __restrict__ scal,
                                             float* __restrict__ d_out,
                                             float* __restrict__ esum) {
    __shared__ float warr[4];
    int t = threadIdx.x;
    int i = blockIdx.x * 256 + t;
    float M = scal[0];
    float p = 0.f;
    if (i < NN) {
        if (ready[i] > 0) p = expf(logits[i] - M);
        d_out[i] = p;
    }
    float s = p;
#pragma unroll
    for (int off = 32; off > 0; off >>= 1) s += __shfl_xor(s, off, 64);
    if ((t & 63) == 0) warr[t >> 6] = s;
    __syncthreads();
    if (t == 0) atomicAdd(esum, warr[0] + warr[1] + warr[2] + warr[3]);
}

// ---------- normalize ----------
__global__ void k_scale(const float* __restrict__ esum, const float* __restrict__ scal,
                        float* __restrict__ d_out) {
    int i = blockIdx.x * blockDim.x + threadIdx.x;
    float inv = 1.0f / (esum[0] + scal[1]);
    if (i < NN) d_out[i] *= inv;
    else if (i == NN) d_out[NN] = scal[1] * inv;
}

extern "C" void kernel_launch(void* const* d_in, const int* in_sizes, int n_in,
                              void* d_out, int out_size, void* d_ws, size_t ws_size,
                              hipStream_t stream) {
    const float* x      = (const float*)d_in[0];
    const int*   edges  = (const int*)d_in[1];
    const float* eattr  = (const float*)d_in[2];
    const int*   ready  = (const int*)d_in[3];
    const float* pe     = (const float*)d_in[4];
    const float* gcn_w  = (const float*)d_in[5];
    const float* gcn_b  = (const float*)d_in[6];
    const float* mlp_w1 = (const float*)d_in[7];
    const float* mlp_b1 = (const float*)d_in[8];
    const float* mlp_w2 = (const float*)d_in[9];
    const float* mlp_b2 = (const float*)d_in[10];
    const float* val_w  = (const float*)d_in[11];
    const float* val_b  = (const float*)d_in[12];
    const float* cl_w   = (const float*)d_in[13];
    const float* cl_b   = (const float*)d_in[14];
    const float* pw1    = (const float*)d_in[15];
    const float* pb1    = (const float*)d_in[16];
    const float* pw2    = (const float*)d_in[17];
    const float* pb2    = (const float*)d_in[18];

    const int* rows = edges;
    const int* cols = edges + EE;

    // workspace layout (~93 MB)
    float* ws      = (float*)d_ws;
    float* dis     = ws;                          // N
    float* logits  = ws + NN;                     // N
    int*   count   = (int*)(ws + 2 * (size_t)NN); // N
    int*   base    = count + NN;                  // N
    int*   endp    = base + NN;                   // N
    int*   bsum    = endp + NN;                   // 256
    float* bufB    = (float*)(bsum + 256);        // N*128 fp32 (gather out / gemm in)
    ushort* bufH   = (ushort*)(bufB + (size_t)NN * HH);  // N*128 bf16 (gemm out / gather in)
    int2*  csre    = (int2*)(bufH + (size_t)NN * HH);    // E (8B each)
    float* meansum = (float*)(csre + EE);         // NREP*128
    unsigned* maxenc  = (unsigned*)(meansum + NREP * HH);  // NREP*128
    unsigned* lmaxenc = maxenc + NREP * HH;
    float* esum    = (float*)(lmaxenc + 1);
    float* scal    = esum + 1;                    // 2
    ushort* wt     = (ushort*)(scal + 2);         // 3*128*128 bf16 transposed weights

    // aliases (lifetime-disjoint):
    //  cnt64 (8N u64, used k_init..k_makeptr) aliases csre (written only by k_fill, later)
    //  fillptr (8N int, used k_makeptr..k_fill) aliases bufB (written first by gather0, later)
    u64* cnt64   = (u64*)csre;
    int* fillptr = (int*)bufB;

    float* out = (float*)d_out;

    const int nb = (NN + 255) / 256;
    const int gb = (NN + 63) / 64;
    const int eb = (EE + 255) / 256;
    const int ab = (NN * 64 + 255) / 256;   // gather: wave per node
    const int ib = (NREP * NN + 255) / 256;

    k_init<<<ib, 256, 0, stream>>>(cnt64, meansum, maxenc, lmaxenc, esum);
    k_prep<<<(3 * HH * HH + 255) / 256, 256, 0, stream>>>(gcn_w, gcn_w + HH * HH, mlp_w1, wt);
    k_deg<<<eb, 256, 0, stream>>>(rows, eattr, cnt64);
    k_red<<<nb, 256, 0, stream>>>(cnt64, count, dis);

    // CSR build
    k_scan1<<<NSCAN, 256, 0, stream>>>(count, base, bsum);
    k_scan2<<<1, 256, 0, stream>>>(bsum);
    k_scan3<<<nb, 256, 0, stream>>>(base, bsum);
    k_makeptr<<<nb, 256, 0, stream>>>(cnt64, base, fillptr, endp);
    k_fill<<<eb, 256, 0, stream>>>(rows, cols, eattr, dis, fillptr, csre);

    // layer 0
    k_mfma<0><<<gb, 256, 0, stream>>>(x, wt, bufH, nullptr, nullptr, nullptr, nullptr,
                                      nullptr, nullptr, nullptr, nullptr, NN);
    k_gather<<<ab, 256, 0, stream>>>(bufH, csre, base, endp, dis, gcn_b, bufB);

    // layer 1 (relu applied on staging of bufB)
    k_mfma<1><<<gb, 256, 0, stream>>>(bufB, wt + HH * HH, bufH, nullptr, nullptr, nullptr,
                                      nullptr, nullptr, nullptr, nullptr, nullptr, NN);
    k_gather<<<ab, 256, 0, stream>>>(bufH, csre, base, endp, dis, gcn_b + HH, bufB);

    // heads
    k_mfma<2><<<gb, 256, 0, stream>>>(bufB, wt + 2 * HH * HH, nullptr, mlp_b1, mlp_w2,
                                      mlp_b2, ready, logits, meansum, maxenc, lmaxenc, NN);
    k_fin1<<<1, 256, 0, stream>>>(meansum, maxenc, lmaxenc, val_w, val_b, pe, cl_w, cl_b,
                                  pw1, pb1, pw2, pb2, scal, out);
    k_exp<<<nb, 256, 0, stream>>>(logits, ready, scal, out, esum);
    k_scale<<<(NN + 1 + 255) / 256, 256, 0, stream>>>(esum, scal, out);
}